// Round 1
// baseline (901.988 us; speedup 1.0000x reference)
//
#include <hip/hip_runtime.h>

typedef unsigned int   u32;
typedef unsigned short u16;

typedef float  f32x4  __attribute__((ext_vector_type(4)));
typedef u32    u32x4  __attribute__((ext_vector_type(4)));
typedef __bf16 bf16x8 __attribute__((ext_vector_type(8)));

union FragU { u16 us[8]; u32x4 q; bf16x8 v; };

__device__ __forceinline__ u32 f2u(float x){ union{float f;u32 u;}c; c.f=x; return c.u; }
__device__ __forceinline__ float u2f(u32 u){ union{float f;u32 u;}c; c.u=u; return c.f; }
__device__ __forceinline__ u16 bfhi(float x){ u32 u=f2u(x); return (u16)((u + 0x7fffu + ((u>>16)&1u))>>16); }
__device__ __forceinline__ float bff(u16 h){ return u2f(((u32)h)<<16); }
// fp32 -> (hi,lo) bf16 pair packed in one u32 (low half = hi part)
__device__ __forceinline__ u32 pack2(float x){
  u16 h = bfhi(x);
  u16 l = bfhi(x - bff(h));
  return (u32)h | ((u32)l << 16);
}

// ---------------------------------------------------------------------------
// GEMM: C[m][n] = sum_k A[m*K+k] * B[n*K+k]   (both operands K-major, fp32)
// 128x128 tile, split-bf16 (K doubled internally), 16x16x32 bf16 MFMA.
// ---------------------------------------------------------------------------
__global__ __launch_bounds__(256)
void gemm_bt(const float* __restrict__ A, const float* __restrict__ B,
             float* __restrict__ C, int M, int N, int K)
{
  __shared__ u16 As[128*64];
  __shared__ u16 Bs[128*64];
  const int tid = threadIdx.x;
  const int lane = tid & 63;
  const int w  = tid >> 6;
  const int wr = w >> 1, wc = w & 1;
  const int ln = lane & 15, lg = lane >> 4;
  const int bm = blockIdx.y, bn = blockIdx.x;
  const int sr = tid >> 3;   // staging row 0..31
  const int sc = tid & 7;    // float4 slot 0..7
  const float* Ap = A + (size_t)(bm*128)*K;
  const float* Bp = B + (size_t)(bn*128)*K;
  f32x4 z = {0.f,0.f,0.f,0.f};
  f32x4 acc[4][4];
  #pragma unroll
  for (int i=0;i<4;i++){
    #pragma unroll
    for (int j=0;j<4;j++) acc[i][j] = z;
  }
  for (int kt = 0; kt < K; kt += 32) {
    __syncthreads();
    float4 av[4], bv[4];
    #pragma unroll
    for (int p=0;p<4;p++){
      int row = sr + p*32;
      av[p] = *reinterpret_cast<const float4*>(Ap + (size_t)row*K + kt + sc*4);
      bv[p] = *reinterpret_cast<const float4*>(Bp + (size_t)row*K + kt + sc*4);
    }
    #pragma unroll
    for (int p=0;p<4;p++){
      int row = sr + p*32;
      int sidx = (row*64 + sc*8) ^ ((row&7)<<3);
      u32x4 pa = { pack2(av[p].x), pack2(av[p].y), pack2(av[p].z), pack2(av[p].w) };
      u32x4 pb = { pack2(bv[p].x), pack2(bv[p].y), pack2(bv[p].z), pack2(bv[p].w) };
      *reinterpret_cast<u32x4*>(&As[sidx]) = pa;
      *reinterpret_cast<u32x4*>(&Bs[sidx]) = pb;
    }
    __syncthreads();
    #pragma unroll
    for (int ks=0; ks<2; ks++){
      const int kb = ks*32 + lg*8;
      FragU af[4], bf_[4];
      #pragma unroll
      for (int mi=0;mi<4;mi++){
        int row = wr*64 + mi*16 + ln;
        af[mi].q = *reinterpret_cast<const u32x4*>(&As[(row*64 + kb) ^ ((row&7)<<3)]);
      }
      #pragma unroll
      for (int ni=0;ni<4;ni++){
        int row = wc*64 + ni*16 + ln;
        bf_[ni].q = *reinterpret_cast<const u32x4*>(&Bs[(row*64 + kb) ^ ((row&7)<<3)]);
      }
      #pragma unroll
      for (int mi=0;mi<4;mi++){
        #pragma unroll
        for (int ni=0;ni<4;ni++)
          acc[mi][ni] = __builtin_amdgcn_mfma_f32_16x16x32_bf16(af[mi].v, bf_[ni].v, acc[mi][ni], 0,0,0);
      }
    }
  }
  #pragma unroll
  for (int mi=0;mi<4;mi++){
    #pragma unroll
    for (int ni=0;ni<4;ni++){
      int row0 = bm*128 + wr*64 + mi*16 + lg*4;
      int col  = bn*128 + wc*64 + ni*16 + ln;
      #pragma unroll
      for (int r2=0;r2<4;r2++)
        C[(size_t)(row0+r2)*N + col] = acc[mi][ni][r2];
    }
  }
}

// ---------------------------------------------------------------------------
// Gather old paged cache into contiguous ws buffers.
// k_all  : [B][HKV][1024][128]  (row-major)
// v_allT : [B][HKV][128][1024]  (transposed: d-major)
// ---------------------------------------------------------------------------
__global__ __launch_bounds__(256)
void copy_cache(const float* __restrict__ k_cache, const float* __restrict__ v_cache,
                const int* __restrict__ page_table,
                float* __restrict__ k_all, float* __restrict__ v_allT)
{
  __shared__ float tb[32][129];
  const int id = blockIdx.x;
  const int jt = id & 31, h = (id>>5)&7, b = id>>8;
  const int tid = threadIdx.x;
  const int j0 = jt*32;
  {
    int r = tid>>3, c = tid&7;
    int j = j0 + r;
    int page = page_table[b*64 + (j>>4)];
    int slot = j & 15;
    const float* ks = k_cache + (size_t)((page*16 + slot)*8 + h)*128;
    const float* vs = v_cache + (size_t)((page*16 + slot)*8 + h)*128;
    float* kd = k_all + ((size_t)(b*8+h)*1024 + j)*128;
    #pragma unroll
    for (int i=0;i<4;i++){
      int d0 = (c + 8*i)*4;
      *reinterpret_cast<float4*>(kd + d0) = *reinterpret_cast<const float4*>(ks + d0);
      float4 v4 = *reinterpret_cast<const float4*>(vs + d0);
      tb[r][d0+0]=v4.x; tb[r][d0+1]=v4.y; tb[r][d0+2]=v4.z; tb[r][d0+3]=v4.w;
    }
  }
  __syncthreads();
  {
    int dout = tid>>1, jh = tid&1;
    float* vd = v_allT + ((size_t)(b*8+h)*128 + dout)*1024 + j0 + jh*16;
    #pragma unroll
    for (int i=0;i<4;i++){
      float4 o;
      o.x = tb[jh*16 + i*4 + 0][dout];
      o.y = tb[jh*16 + i*4 + 1][dout];
      o.z = tb[jh*16 + i*4 + 2][dout];
      o.w = tb[jh*16 + i*4 + 3][dout];
      *reinterpret_cast<float4*>(vd + i*4) = o;
    }
  }
}

// ---------------------------------------------------------------------------
// Per-head RMSNorm + partial RoPE (first 64 dims) + scatter new K/V into
// k_all / v_allT.  One block per token, one wave per head iteration.
// ---------------------------------------------------------------------------
__global__ __launch_bounds__(256)
void norm_rope_scatter(float* __restrict__ qkv, const float* __restrict__ cosT,
                       const float* __restrict__ sinT, const int* __restrict__ positions,
                       const int* __restrict__ cache_seqlens,
                       const float* __restrict__ qw, const float* __restrict__ kw,
                       float* __restrict__ k_all, float* __restrict__ v_allT)
{
  const int t = blockIdx.x;
  const int lane = threadIdx.x & 63;
  const int w = threadIdx.x >> 6;
  const int b = t >> 9;        // QL = 512
  const int q = t & 511;
  const int pos  = positions[t];
  const int cpos = cache_seqlens[b] + q;
  for (int it=0; it<12; ++it){
    int h = it*4 + w;          // 0..47
    float* xp = qkv + (size_t)t*6144 + h*128 + 2*lane;
    float2 x = *reinterpret_cast<const float2*>(xp);
    if (h < 40){               // q + k heads get RMSNorm + RoPE
      float ss = x.x*x.x + x.y*x.y;
      #pragma unroll
      for (int mk=1; mk<64; mk<<=1) ss += __shfl_xor(ss, mk);
      float var = ss*(1.0f/128.0f) + 1e-6f;
      float rq = rsqrtf(var);
      rq = rq*(1.5f - 0.5f*var*rq*rq);   // Newton refine
      const float* wt = (h<32) ? qw : kw;
      x.x *= rq*wt[2*lane]; x.y *= rq*wt[2*lane+1];
      float px = __shfl_xor(x.x, 16);
      float py = __shfl_xor(x.y, 16);
      if (lane < 32){
        int ci = pos*32 + 2*(lane&15);
        float2 cc = *reinterpret_cast<const float2*>(cosT + ci);
        float2 sc = *reinterpret_cast<const float2*>(sinT + ci);
        if (lane < 16){ x.x = x.x*cc.x - px*sc.x; x.y = x.y*cc.y - py*sc.y; }
        else          { x.x = x.x*cc.x + px*sc.x; x.y = x.y*cc.y + py*sc.y; }
      }
    }
    if (h < 32){
      *reinterpret_cast<float2*>(xp) = x;   // q back in place
    } else if (h < 40){
      *reinterpret_cast<float2*>(k_all + ((size_t)(b*8 + (h-32))*1024 + cpos)*128 + 2*lane) = x;
    } else {
      float* vp = v_allT + ((size_t)(b*8 + (h-40))*128 + 2*lane)*1024 + cpos;
      vp[0]    = x.x;
      vp[1024] = x.y;
    }
  }
}

// ---------------------------------------------------------------------------
// Fused GQA causal attention.  Block = (b, kv-head, g, 64-row q tile),
// 4 waves x 16 q-rows. KV tiles of 32, split-bf16 MFMA, fp32 online softmax.
// ---------------------------------------------------------------------------
__global__ __launch_bounds__(256)
void attn_fused(const float* __restrict__ qkv, const float* __restrict__ k_all,
                const float* __restrict__ v_allT, const int* __restrict__ cache_seqlens,
                float* __restrict__ attnO)
{
  __shared__ u16 Ks[32*256];     // [kv][k'=2d+s]  (swizzled)
  __shared__ u16 Vs[128*64];     // [d][k''=2kv+s] (swizzled)
  __shared__ float Pl[4*16*32];  // per-wave P tile (swizzled)
  const int tid = threadIdx.x, lane = tid&63, w = tid>>6;
  const int ln = lane&15, lg = lane>>4;
  const int id = blockIdx.x;
  const int qt = id & 7, g = (id>>3)&3, kvh = (id>>5)&7, b = id>>8;
  const int cs = cache_seqlens[b];
  const int h  = kvh*4 + g;
  const int q0 = qt*64 + w*16;
  const float SCALE = 0.08838834764831845f;  // 1/sqrt(128)
  f32x4 z = {0.f,0.f,0.f,0.f};

  FragU qf[8];
  {
    const float* qp = qkv + (size_t)(b*512 + q0 + ln)*6144 + h*128;
    #pragma unroll
    for (int ks=0; ks<8; ks++){
      int d0 = ks*16 + lg*4;
      float4 v4 = *reinterpret_cast<const float4*>(qp + d0);
      qf[ks].q = (u32x4){ pack2(v4.x*SCALE), pack2(v4.y*SCALE),
                          pack2(v4.z*SCALE), pack2(v4.w*SCALE) };
    }
  }
  f32x4 O[8];
  #pragma unroll
  for (int i=0;i<8;i++) O[i] = z;
  float m[4] = {-1e30f,-1e30f,-1e30f,-1e30f};
  float l[4] = {0.f,0.f,0.f,0.f};
  const int prow0 = cs + q0 + lg*4;
  const int ntiles = (cs + qt*64 + 64 + 31) >> 5;
  const float* kbase = k_all  + (size_t)(b*8+kvh)*1024*128;
  const float* vbase = v_allT + (size_t)(b*8+kvh)*128*1024;

  for (int tile=0; tile<ntiles; ++tile){
    const int kv0 = tile*32;
    __syncthreads();
    {   // stage K tile (32 kv x 128 d) as split-bf16
      int r = tid>>3;
      const float* kp = kbase + (size_t)(kv0 + r)*128;
      #pragma unroll
      for (int c2=0;c2<4;c2++){
        int d0 = ((tid&7) + 8*c2)*4;
        float4 v4 = *reinterpret_cast<const float4*>(kp + d0);
        u32x4 pk = { pack2(v4.x), pack2(v4.y), pack2(v4.z), pack2(v4.w) };
        *reinterpret_cast<u32x4*>(&Ks[(r*256 + d0*2) ^ ((r&7)<<3)]) = pk;
      }
    }
    {   // stage V tile (transposed source) as split-bf16 along kv
      int dr = tid>>1;
      const float* vp = vbase + (size_t)dr*1024 + kv0;
      #pragma unroll
      for (int c2=0;c2<4;c2++){
        int kl0 = ((tid&1)*4 + c2)*4;
        float4 v4 = *reinterpret_cast<const float4*>(vp + kl0);
        u32x4 pv4 = { pack2(v4.x), pack2(v4.y), pack2(v4.z), pack2(v4.w) };
        *reinterpret_cast<u32x4*>(&Vs[(dr*64 + kl0*2) ^ ((dr&7)<<3)]) = pv4;
      }
    }
    __syncthreads();
    // S = Q K^T (split-bf16 over K'=256)
    f32x4 s[2]; s[0]=z; s[1]=z;
    #pragma unroll
    for (int ks=0; ks<8; ks++){
      int kb = ks*32 + lg*8;
      #pragma unroll
      for (int n=0;n<2;n++){
        int kr = n*16 + ln;
        FragU kf;
        kf.q = *reinterpret_cast<const u32x4*>(&Ks[(kr*256 + kb) ^ ((kr&7)<<3)]);
        s[n] = __builtin_amdgcn_mfma_f32_16x16x32_bf16(qf[ks].v, kf.v, s[n], 0,0,0);
      }
    }
    // online softmax (rows = lg*4+r)
    float mx[4];
    #pragma unroll
    for (int r=0;r<4;r++){
      int pr = prow0 + r;
      float a0 = (kv0 + ln      <= pr) ? s[0][r] : -1e30f;
      float a1 = (kv0 + 16 + ln <= pr) ? s[1][r] : -1e30f;
      mx[r] = fmaxf(a0, a1);
    }
    #pragma unroll
    for (int off=1; off<16; off<<=1){
      #pragma unroll
      for (int r=0;r<4;r++) mx[r] = fmaxf(mx[r], __shfl_xor(mx[r], off));
    }
    float corr[4];
    #pragma unroll
    for (int r=0;r<4;r++){
      float mn = fmaxf(m[r], mx[r]);
      corr[r] = __expf(m[r] - mn);
      m[r] = mn;
    }
    float pv[2][4], ps[4] = {0.f,0.f,0.f,0.f};
    #pragma unroll
    for (int n=0;n<2;n++){
      #pragma unroll
      for (int r=0;r<4;r++){
        bool ok = (kv0 + n*16 + ln) <= (prow0 + r);
        float p = ok ? __expf(s[n][r] - m[r]) : 0.f;
        pv[n][r] = p;
        ps[r] += p;
      }
    }
    #pragma unroll
    for (int off=1; off<16; off<<=1){
      #pragma unroll
      for (int r=0;r<4;r++) ps[r] += __shfl_xor(ps[r], off);
    }
    #pragma unroll
    for (int r=0;r<4;r++) l[r] = l[r]*corr[r] + ps[r];
    #pragma unroll
    for (int nf=0; nf<8; nf++){
      #pragma unroll
      for (int r=0;r<4;r++) O[nf][r] = O[nf][r]*corr[r];
    }
    // P -> per-wave LDS (swizzled), then build duplicated hi/lo A-frags
    #pragma unroll
    for (int n=0;n<2;n++){
      #pragma unroll
      for (int r=0;r<4;r++){
        int row = lg*4 + r;
        Pl[w*512 + ((row*32 + n*16 + ln) ^ ((row&7)<<2))] = pv[n][r];
      }
    }
    FragU pah[2], pal[2];
    #pragma unroll
    for (int ks2=0; ks2<2; ks2++){
      int fi = (ln*32 + ks2*16 + lg*4) ^ ((ln&7)<<2);
      float4 pp = *reinterpret_cast<const float4*>(&Pl[w*512 + fi]);
      float parr[4] = {pp.x, pp.y, pp.z, pp.w};
      #pragma unroll
      for (int i=0;i<4;i++){
        u16 hh = bfhi(parr[i]);
        u16 ll = bfhi(parr[i] - bff(hh));
        pah[ks2].us[2*i] = hh; pah[ks2].us[2*i+1] = hh;
        pal[ks2].us[2*i] = ll; pal[ks2].us[2*i+1] = ll;
      }
    }
    // O += (Ph+Pl) x (Vh+Vl)
    #pragma unroll
    for (int nf=0; nf<8; nf++){
      int dr = nf*16 + ln;
      #pragma unroll
      for (int ks2=0; ks2<2; ks2++){
        FragU vf;
        vf.q = *reinterpret_cast<const u32x4*>(&Vs[(dr*64 + ks2*32 + lg*8) ^ ((dr&7)<<3)]);
        O[nf] = __builtin_amdgcn_mfma_f32_16x16x32_bf16(pah[ks2].v, vf.v, O[nf], 0,0,0);
        O[nf] = __builtin_amdgcn_mfma_f32_16x16x32_bf16(pal[ks2].v, vf.v, O[nf], 0,0,0);
      }
    }
  }
  float il[4];
  #pragma unroll
  for (int r=0;r<4;r++) il[r] = 1.0f / l[r];
  float* op = attnO + (size_t)(b*512 + q0 + lg*4)*4096 + h*128 + ln;
  #pragma unroll
  for (int nf=0; nf<8; nf++){
    #pragma unroll
    for (int r=0;r<4;r++)
      op[(size_t)r*4096 + nf*16] = O[nf][r] * il[r];
  }
}

// ---------------------------------------------------------------------------
extern "C" void kernel_launch(void* const* d_in, const int* in_sizes, int n_in,
                              void* d_out, int out_size, void* d_ws, size_t ws_size,
                              hipStream_t stream) {
  const float* hidden    = (const float*)d_in[0];
  const float* cosT      = (const float*)d_in[1];
  const float* sinT      = (const float*)d_in[2];
  const int*   positions = (const int*)  d_in[3];
  const float* k_cache   = (const float*)d_in[4];
  const float* v_cache   = (const float*)d_in[5];
  const int*   page_tab  = (const int*)  d_in[6];
  const int*   cache_sl  = (const int*)  d_in[7];
  const float* qkv_w     = (const float*)d_in[9];
  const float* o_w       = (const float*)d_in[10];
  const float* qnw       = (const float*)d_in[11];
  const float* knw       = (const float*)d_in[12];
  float* out = (float*)d_out;

  float* ws     = (float*)d_ws;
  float* qkv    = ws;                       // 2048*6144 = 12582912
  float* k_all  = qkv   + 12582912;         // 4*8*1024*128 = 4194304
  float* v_allT = k_all + 4194304;          // 4194304
  float* attnB  = v_allT + 4194304;         // 2048*4096 = 8388608
  (void)in_sizes; (void)n_in; (void)out_size; (void)ws_size;

  hipLaunchKernelGGL(copy_cache, dim3(1024), dim3(256), 0, stream,
                     k_cache, v_cache, page_tab, k_all, v_allT);
  hipLaunchKernelGGL(gemm_bt, dim3(48,16), dim3(256), 0, stream,
                     hidden, qkv_w, qkv, 2048, 6144, 4096);
  hipLaunchKernelGGL(norm_rope_scatter, dim3(2048), dim3(256), 0, stream,
                     qkv, cosT, sinT, positions, cache_sl, qnw, knw, k_all, v_allT);
  hipLaunchKernelGGL(attn_fused, dim3(1024), dim3(256), 0, stream,
                     qkv, k_all, v_allT, cache_sl, attnB);
  hipLaunchKernelGGL(gemm_bt, dim3(32,16), dim3(256), 0, stream,
                     attnB, o_w, out, 2048, 4096, 4096);
}

// Round 2
// 890.812 us; speedup vs baseline: 1.0125x; 1.0125x over previous
//
#include <hip/hip_runtime.h>

typedef unsigned int   u32;
typedef unsigned short u16;

typedef float  f32x4  __attribute__((ext_vector_type(4)));
typedef u32    u32x4  __attribute__((ext_vector_type(4)));
typedef __bf16 bf16x8 __attribute__((ext_vector_type(8)));

union FragU { u16 us[8]; u32x4 q; bf16x8 v; };

__device__ __forceinline__ u32 f2u(float x){ union{float f;u32 u;}c; c.f=x; return c.u; }
__device__ __forceinline__ float u2f(u32 u){ union{float f;u32 u;}c; c.u=u; return c.f; }
__device__ __forceinline__ u16 bfhi(float x){ u32 u=f2u(x); return (u16)((u + 0x7fffu + ((u>>16)&1u))>>16); }
__device__ __forceinline__ float bff(u16 h){ return u2f(((u32)h)<<16); }
// fp32 -> (hi,lo) bf16 pair packed in one u32 (low half = hi part)
__device__ __forceinline__ u32 pack2(float x){
  u16 h = bfhi(x);
  u16 l = bfhi(x - bff(h));
  return (u32)h | ((u32)l << 16);
}

__device__ __forceinline__ void gload16(const void* g, void* l){
  __builtin_amdgcn_global_load_lds(
      (const __attribute__((address_space(1))) unsigned int*)g,
      (__attribute__((address_space(3))) unsigned int*)l, 16, 0, 0);
}

// ---------------------------------------------------------------------------
// Elementwise fp32 -> packed split-bf16 (u32 per element).
// ---------------------------------------------------------------------------
__global__ __launch_bounds__(256)
void split_pack(const float* __restrict__ in, u32* __restrict__ out, int n4)
{
  int i = blockIdx.x*256 + threadIdx.x;
  const int stride = gridDim.x*256;
  for (; i < n4; i += stride){
    float4 v = reinterpret_cast<const float4*>(in)[i];
    reinterpret_cast<u32x4*>(out)[i] =
      (u32x4){ pack2(v.x), pack2(v.y), pack2(v.z), pack2(v.w) };
  }
}

// ---------------------------------------------------------------------------
// GEMM on pre-packed split-bf16: C[m][n] = sum A[m][2K] * B[n][2K] (bf16 MFMA)
// A,B are u32[rows][K] (each u32 = (hi,lo) bf16 pair -> bf16 row of length 2K).
// m97 structure: 128x128 tile, BK=64 bf16, global_load_lds width 16, 2-barrier.
// ---------------------------------------------------------------------------
__global__ __launch_bounds__(256)
void gemm_pk(const u32* __restrict__ A, const u32* __restrict__ B,
             float* __restrict__ C, int M, int N, int K)  // K = u32 per row
{
  __shared__ u16 As[128*64];
  __shared__ u16 Bs[128*64];
  const int tid  = threadIdx.x;
  const int lane = tid & 63;
  const int w    = tid >> 6;
  const int wr = w >> 1, wc = w & 1;
  const int ln = lane & 15, lg = lane >> 4;
  // XCD-bijective swizzle (grid % 8 == 0 guaranteed by launch)
  const int nbn = N >> 7;
  const int nwg = (M >> 7) * nbn;
  const int bid = blockIdx.x;
  const int swz = (bid & 7) * (nwg >> 3) + (bid >> 3);
  const int bm = swz / nbn, bn = swz % nbn;

  const size_t rowb = (size_t)K * 4;           // row bytes
  const char* Ab = (const char*)(A + (size_t)(bm*128)*K) + (lane>>3)*rowb + (lane&7)*16;
  const char* Bb = (const char*)(B + (size_t)(bn*128)*K) + (lane>>3)*rowb + (lane&7)*16;

  f32x4 z = {0.f,0.f,0.f,0.f};
  f32x4 acc[4][4];
  #pragma unroll
  for (int i=0;i<4;i++){
    #pragma unroll
    for (int j=0;j<4;j++) acc[i][j] = z;
  }

  const int K2 = 2*K;
  for (int kt = 0; kt < K2; kt += 64) {
    const size_t kb2 = (size_t)kt*2;
    #pragma unroll
    for (int i=0;i<4;i++){
      const int r0 = (w*4+i)*8;
      gload16(Ab + (size_t)r0*rowb + kb2, &As[r0*64]);
      gload16(Bb + (size_t)r0*rowb + kb2, &Bs[r0*64]);
    }
    __syncthreads();
    #pragma unroll
    for (int ks=0; ks<2; ks++){
      FragU af[4], bfr[4];
      #pragma unroll
      for (int mi=0;mi<4;mi++){
        int row = wr*64 + mi*16 + ln;
        af[mi].q = *reinterpret_cast<const u32x4*>(&As[row*64 + ks*32 + lg*8]);
      }
      #pragma unroll
      for (int ni=0;ni<4;ni++){
        int row = wc*64 + ni*16 + ln;
        bfr[ni].q = *reinterpret_cast<const u32x4*>(&Bs[row*64 + ks*32 + lg*8]);
      }
      #pragma unroll
      for (int mi=0;mi<4;mi++){
        #pragma unroll
        for (int ni=0;ni<4;ni++)
          acc[mi][ni] = __builtin_amdgcn_mfma_f32_16x16x32_bf16(af[mi].v, bfr[ni].v, acc[mi][ni], 0,0,0);
      }
    }
    __syncthreads();
  }
  #pragma unroll
  for (int mi=0;mi<4;mi++){
    #pragma unroll
    for (int ni=0;ni<4;ni++){
      int row0 = bm*128 + wr*64 + mi*16 + lg*4;
      int col  = bn*128 + wc*64 + ni*16 + ln;
      #pragma unroll
      for (int r2=0;r2<4;r2++)
        C[(size_t)(row0+r2)*N + col] = acc[mi][ni][r2];
    }
  }
}

// ---------------------------------------------------------------------------
// Gather old paged cache into contiguous PACKED ws buffers.
// k_all  : u32 [B][HKV][1024][128]   v_allT : u32 [B][HKV][128][1024]
// ---------------------------------------------------------------------------
__global__ __launch_bounds__(256)
void copy_cache(const float* __restrict__ k_cache, const float* __restrict__ v_cache,
                const int* __restrict__ page_table,
                u32* __restrict__ k_all, u32* __restrict__ v_allT)
{
  __shared__ float tb[32][129];
  const int id = blockIdx.x;
  const int jt = id & 31, h = (id>>5)&7, b = id>>8;
  const int tid = threadIdx.x;
  const int j0 = jt*32;
  {
    int r = tid>>3, c = tid&7;
    int j = j0 + r;
    int page = page_table[b*64 + (j>>4)];
    int slot = j & 15;
    const float* ks = k_cache + (size_t)((page*16 + slot)*8 + h)*128;
    const float* vs = v_cache + (size_t)((page*16 + slot)*8 + h)*128;
    u32* kd = k_all + ((size_t)(b*8+h)*1024 + j)*128;
    #pragma unroll
    for (int i=0;i<4;i++){
      int d0 = (c + 8*i)*4;
      float4 k4 = *reinterpret_cast<const float4*>(ks + d0);
      *reinterpret_cast<u32x4*>(kd + d0) =
        (u32x4){ pack2(k4.x), pack2(k4.y), pack2(k4.z), pack2(k4.w) };
      float4 v4 = *reinterpret_cast<const float4*>(vs + d0);
      tb[r][d0+0]=v4.x; tb[r][d0+1]=v4.y; tb[r][d0+2]=v4.z; tb[r][d0+3]=v4.w;
    }
  }
  __syncthreads();
  {
    int dout = tid>>1, jh = tid&1;
    u32* vd = v_allT + ((size_t)(b*8+h)*128 + dout)*1024 + j0 + jh*16;
    #pragma unroll
    for (int i=0;i<4;i++){
      u32x4 o;
      o.x = pack2(tb[jh*16 + i*4 + 0][dout]);
      o.y = pack2(tb[jh*16 + i*4 + 1][dout]);
      o.z = pack2(tb[jh*16 + i*4 + 2][dout]);
      o.w = pack2(tb[jh*16 + i*4 + 3][dout]);
      *reinterpret_cast<u32x4*>(vd + i*4) = o;
    }
  }
}

// ---------------------------------------------------------------------------
// Per-head RMSNorm + partial RoPE + scatter new K/V (packed) into k_all/v_allT.
// ---------------------------------------------------------------------------
__global__ __launch_bounds__(256)
void norm_rope_scatter(float* __restrict__ qkv, const float* __restrict__ cosT,
                       const float* __restrict__ sinT, const int* __restrict__ positions,
                       const int* __restrict__ cache_seqlens,
                       const float* __restrict__ qw, const float* __restrict__ kw,
                       u32* __restrict__ k_all, u32* __restrict__ v_allT)
{
  const int t = blockIdx.x;
  const int lane = threadIdx.x & 63;
  const int w = threadIdx.x >> 6;
  const int b = t >> 9;        // QL = 512
  const int q = t & 511;
  const int pos  = positions[t];
  const int cpos = cache_seqlens[b] + q;
  for (int it=0; it<12; ++it){
    int h = it*4 + w;          // 0..47
    float* xp = qkv + (size_t)t*6144 + h*128 + 2*lane;
    float2 x = *reinterpret_cast<const float2*>(xp);
    if (h < 40){               // q + k heads get RMSNorm + RoPE
      float ss = x.x*x.x + x.y*x.y;
      #pragma unroll
      for (int mk=1; mk<64; mk<<=1) ss += __shfl_xor(ss, mk);
      float var = ss*(1.0f/128.0f) + 1e-6f;
      float rq = rsqrtf(var);
      rq = rq*(1.5f - 0.5f*var*rq*rq);   // Newton refine
      const float* wt = (h<32) ? qw : kw;
      x.x *= rq*wt[2*lane]; x.y *= rq*wt[2*lane+1];
      float px = __shfl_xor(x.x, 16);
      float py = __shfl_xor(x.y, 16);
      if (lane < 32){
        int ci = pos*32 + 2*(lane&15);
        float2 cc = *reinterpret_cast<const float2*>(cosT + ci);
        float2 sc = *reinterpret_cast<const float2*>(sinT + ci);
        if (lane < 16){ x.x = x.x*cc.x - px*sc.x; x.y = x.y*cc.y - py*sc.y; }
        else          { x.x = x.x*cc.x + px*sc.x; x.y = x.y*cc.y + py*sc.y; }
      }
    }
    if (h < 32){
      *reinterpret_cast<float2*>(xp) = x;   // q back in place (fp32)
    } else if (h < 40){
      u32* kp = k_all + ((size_t)(b*8 + (h-32))*1024 + cpos)*128 + 2*lane;
      kp[0] = pack2(x.x); kp[1] = pack2(x.y);
    } else {
      u32* vp = v_allT + ((size_t)(b*8 + (h-40))*128 + 2*lane)*1024 + cpos;
      vp[0]    = pack2(x.x);
      vp[1024] = pack2(x.y);
    }
  }
}

// ---------------------------------------------------------------------------
// Fused GQA causal attention.  Block = (b, kv-head, g, 64-row q tile),
// 4 waves x 16 q-rows. KV tiles of 32, split-bf16 MFMA, fp32 online softmax.
// K/V come pre-packed; output written PACKED for the O-proj GEMM.
// ---------------------------------------------------------------------------
__global__ __launch_bounds__(256)
void attn_fused(const float* __restrict__ qkv, const u32* __restrict__ k_all,
                const u32* __restrict__ v_allT, const int* __restrict__ cache_seqlens,
                u32* __restrict__ attnO)
{
  __shared__ u16 Ks[32*256];     // [kv][k'=2d+s]  (swizzled)
  __shared__ u16 Vs[128*64];     // [d][k''=2kv+s] (swizzled)
  __shared__ float Pl[4*16*32];  // per-wave P tile (swizzled)
  const int tid = threadIdx.x, lane = tid&63, w = tid>>6;
  const int ln = lane&15, lg = lane>>4;
  const int id = blockIdx.x;
  const int qt = id & 7, g = (id>>3)&3, kvh = (id>>5)&7, b = id>>8;
  const int cs = cache_seqlens[b];
  const int h  = kvh*4 + g;
  const int q0 = qt*64 + w*16;
  const float SCALE = 0.08838834764831845f;  // 1/sqrt(128)
  f32x4 z = {0.f,0.f,0.f,0.f};

  FragU qf[8];
  {
    const float* qp = qkv + (size_t)(b*512 + q0 + ln)*6144 + h*128;
    #pragma unroll
    for (int ks=0; ks<8; ks++){
      int d0 = ks*16 + lg*4;
      float4 v4 = *reinterpret_cast<const float4*>(qp + d0);
      qf[ks].q = (u32x4){ pack2(v4.x*SCALE), pack2(v4.y*SCALE),
                          pack2(v4.z*SCALE), pack2(v4.w*SCALE) };
    }
  }
  f32x4 O[8];
  #pragma unroll
  for (int i=0;i<8;i++) O[i] = z;
  float m[4] = {-1e30f,-1e30f,-1e30f,-1e30f};
  float l[4] = {0.f,0.f,0.f,0.f};
  const int prow0 = cs + q0 + lg*4;
  const int ntiles = (cs + qt*64 + 64 + 31) >> 5;
  const u32* kbase = k_all  + (size_t)(b*8+kvh)*1024*128;
  const u32* vbase = v_allT + (size_t)(b*8+kvh)*128*1024;

  for (int tile=0; tile<ntiles; ++tile){
    const int kv0 = tile*32;
    __syncthreads();
    {   // stage K tile (32 kv x 128 d), already packed
      int r = tid>>3;
      const u32* kp = kbase + (size_t)(kv0 + r)*128;
      #pragma unroll
      for (int c2=0;c2<4;c2++){
        int d0 = ((tid&7) + 8*c2)*4;
        u32x4 pk = *reinterpret_cast<const u32x4*>(kp + d0);
        *reinterpret_cast<u32x4*>(&Ks[(r*256 + d0*2) ^ ((r&7)<<3)]) = pk;
      }
    }
    {   // stage V tile (transposed source), already packed
      int dr = tid>>1;
      const u32* vp = vbase + (size_t)dr*1024 + kv0;
      #pragma unroll
      for (int c2=0;c2<4;c2++){
        int kl0 = ((tid&1)*4 + c2)*4;
        u32x4 pv4 = *reinterpret_cast<const u32x4*>(vp + kl0);
        *reinterpret_cast<u32x4*>(&Vs[(dr*64 + kl0*2) ^ ((dr&7)<<3)]) = pv4;
      }
    }
    __syncthreads();
    // S = Q K^T (split-bf16 over K'=256)
    f32x4 s[2]; s[0]=z; s[1]=z;
    #pragma unroll
    for (int ks=0; ks<8; ks++){
      int kb = ks*32 + lg*8;
      #pragma unroll
      for (int n=0;n<2;n++){
        int kr = n*16 + ln;
        FragU kf;
        kf.q = *reinterpret_cast<const u32x4*>(&Ks[(kr*256 + kb) ^ ((kr&7)<<3)]);
        s[n] = __builtin_amdgcn_mfma_f32_16x16x32_bf16(qf[ks].v, kf.v, s[n], 0,0,0);
      }
    }
    // online softmax (rows = lg*4+r)
    float mx[4];
    #pragma unroll
    for (int r=0;r<4;r++){
      int pr = prow0 + r;
      float a0 = (kv0 + ln      <= pr) ? s[0][r] : -1e30f;
      float a1 = (kv0 + 16 + ln <= pr) ? s[1][r] : -1e30f;
      mx[r] = fmaxf(a0, a1);
    }
    #pragma unroll
    for (int off=1; off<16; off<<=1){
      #pragma unroll
      for (int r=0;r<4;r++) mx[r] = fmaxf(mx[r], __shfl_xor(mx[r], off));
    }
    float corr[4];
    #pragma unroll
    for (int r=0;r<4;r++){
      float mn = fmaxf(m[r], mx[r]);
      corr[r] = __expf(m[r] - mn);
      m[r] = mn;
    }
    float pv[2][4], ps[4] = {0.f,0.f,0.f,0.f};
    #pragma unroll
    for (int n=0;n<2;n++){
      #pragma unroll
      for (int r=0;r<4;r++){
        bool ok = (kv0 + n*16 + ln) <= (prow0 + r);
        float p = ok ? __expf(s[n][r] - m[r]) : 0.f;
        pv[n][r] = p;
        ps[r] += p;
      }
    }
    #pragma unroll
    for (int off=1; off<16; off<<=1){
      #pragma unroll
      for (int r=0;r<4;r++) ps[r] += __shfl_xor(ps[r], off);
    }
    #pragma unroll
    for (int r=0;r<4;r++) l[r] = l[r]*corr[r] + ps[r];
    #pragma unroll
    for (int nf=0; nf<8; nf++){
      #pragma unroll
      for (int r=0;r<4;r++) O[nf][r] = O[nf][r]*corr[r];
    }
    // P -> per-wave LDS (swizzled), then build duplicated hi/lo A-frags
    #pragma unroll
    for (int n=0;n<2;n++){
      #pragma unroll
      for (int r=0;r<4;r++){
        int row = lg*4 + r;
        Pl[w*512 + ((row*32 + n*16 + ln) ^ ((row&7)<<2))] = pv[n][r];
      }
    }
    FragU pah[2], pal[2];
    #pragma unroll
    for (int ks2=0; ks2<2; ks2++){
      int fi = (ln*32 + ks2*16 + lg*4) ^ ((ln&7)<<2);
      float4 pp = *reinterpret_cast<const float4*>(&Pl[w*512 + fi]);
      float parr[4] = {pp.x, pp.y, pp.z, pp.w};
      #pragma unroll
      for (int i=0;i<4;i++){
        u16 hh = bfhi(parr[i]);
        u16 ll = bfhi(parr[i] - bff(hh));
        pah[ks2].us[2*i] = hh; pah[ks2].us[2*i+1] = hh;
        pal[ks2].us[2*i] = ll; pal[ks2].us[2*i+1] = ll;
      }
    }
    // O += (Ph+Pl) x (Vh+Vl)
    #pragma unroll
    for (int nf=0; nf<8; nf++){
      int dr = nf*16 + ln;
      #pragma unroll
      for (int ks2=0; ks2<2; ks2++){
        FragU vf;
        vf.q = *reinterpret_cast<const u32x4*>(&Vs[(dr*64 + ks2*32 + lg*8) ^ ((dr&7)<<3)]);
        O[nf] = __builtin_amdgcn_mfma_f32_16x16x32_bf16(pah[ks2].v, vf.v, O[nf], 0,0,0);
        O[nf] = __builtin_amdgcn_mfma_f32_16x16x32_bf16(pal[ks2].v, vf.v, O[nf], 0,0,0);
      }
    }
  }
  float il[4];
  #pragma unroll
  for (int r=0;r<4;r++) il[r] = 1.0f / l[r];
  u32* op = attnO + (size_t)(b*512 + q0 + lg*4)*4096 + h*128 + ln;
  #pragma unroll
  for (int nf=0; nf<8; nf++){
    #pragma unroll
    for (int r=0;r<4;r++)
      op[(size_t)r*4096 + nf*16] = pack2(O[nf][r] * il[r]);
  }
}

// ---------------------------------------------------------------------------
extern "C" void kernel_launch(void* const* d_in, const int* in_sizes, int n_in,
                              void* d_out, int out_size, void* d_ws, size_t ws_size,
                              hipStream_t stream) {
  const float* hidden    = (const float*)d_in[0];
  const float* cosT      = (const float*)d_in[1];
  const float* sinT      = (const float*)d_in[2];
  const int*   positions = (const int*)  d_in[3];
  const float* k_cache   = (const float*)d_in[4];
  const float* v_cache   = (const float*)d_in[5];
  const int*   page_tab  = (const int*)  d_in[6];
  const int*   cache_sl  = (const int*)  d_in[7];
  const float* qkv_w     = (const float*)d_in[9];
  const float* o_w       = (const float*)d_in[10];
  const float* qnw       = (const float*)d_in[11];
  const float* knw       = (const float*)d_in[12];
  float* out = (float*)d_out;

  u32* ws      = (u32*)d_ws;
  float* qkv   = (float*)ws;                // 2048*6144        = 12582912
  u32* k_all   = ws      + 12582912;        // 4*8*1024*128     =  4194304
  u32* v_allT  = k_all   + 4194304;         //                  =  4194304
  u32* attnPk  = v_allT  + 4194304;         // 2048*4096        =  8388608
  u32* hidPk   = attnPk  + 8388608;         // 2048*4096        =  8388608
  u32* qkvwPk  = hidPk   + 8388608;         // 6144*4096        = 25165824
  u32* owPk    = qkvwPk  + 25165824;        // 4096*4096        = 16777216
  (void)in_sizes; (void)n_in; (void)out_size; (void)ws_size;

  hipLaunchKernelGGL(split_pack, dim3(1024), dim3(256), 0, stream,
                     hidden, hidPk, 2097152);
  hipLaunchKernelGGL(split_pack, dim3(1024), dim3(256), 0, stream,
                     qkv_w, qkvwPk, 6291456);
  hipLaunchKernelGGL(split_pack, dim3(1024), dim3(256), 0, stream,
                     o_w, owPk, 4194304);
  hipLaunchKernelGGL(copy_cache, dim3(1024), dim3(256), 0, stream,
                     k_cache, v_cache, page_tab, k_all, v_allT);
  hipLaunchKernelGGL(gemm_pk, dim3(768), dim3(256), 0, stream,
                     hidPk, qkvwPk, qkv, 2048, 6144, 4096);
  hipLaunchKernelGGL(norm_rope_scatter, dim3(2048), dim3(256), 0, stream,
                     qkv, cosT, sinT, positions, cache_sl, qnw, knw, k_all, v_allT);
  hipLaunchKernelGGL(attn_fused, dim3(1024), dim3(256), 0, stream,
                     qkv, k_all, v_allT, cache_sl, attnPk);
  hipLaunchKernelGGL(gemm_pk, dim3(512), dim3(256), 0, stream,
                     attnPk, owPk, out, 2048, 4096, 4096);
}

// Round 3
// 735.715 us; speedup vs baseline: 1.2260x; 1.2108x over previous
//
#include <hip/hip_runtime.h>

typedef unsigned int   u32;
typedef unsigned short u16;

typedef float  f32x4  __attribute__((ext_vector_type(4)));
typedef u32    u32x4  __attribute__((ext_vector_type(4)));
typedef __bf16 bf16x8 __attribute__((ext_vector_type(8)));

union FragU { u16 us[8]; u32x4 q; bf16x8 v; };

__device__ __forceinline__ u32 f2u(float x){ union{float f;u32 u;}c; c.f=x; return c.u; }
__device__ __forceinline__ float u2f(u32 u){ union{float f;u32 u;}c; c.u=u; return c.f; }
__device__ __forceinline__ u16 bfhi(float x){ u32 u=f2u(x); return (u16)((u + 0x7fffu + ((u>>16)&1u))>>16); }
__device__ __forceinline__ float bff(u16 h){ return u2f(((u32)h)<<16); }
// fp32 -> (hi,lo) bf16 pair packed in one u32 (low half = hi part)
__device__ __forceinline__ u32 pack2(float x){
  u16 h = bfhi(x);
  u16 l = bfhi(x - bff(h));
  return (u32)h | ((u32)l << 16);
}

__device__ __forceinline__ void gload16(const void* g, void* l){
  __builtin_amdgcn_global_load_lds(
      (const __attribute__((address_space(1))) unsigned int*)g,
      (__attribute__((address_space(3))) unsigned int*)l, 16, 0, 0);
}

// ---------------------------------------------------------------------------
// Elementwise fp32 -> packed split-bf16 (u32 per element).
// ---------------------------------------------------------------------------
__global__ __launch_bounds__(256)
void split_pack(const float* __restrict__ in, u32* __restrict__ out, int n4)
{
  int i = blockIdx.x*256 + threadIdx.x;
  const int stride = gridDim.x*256;
  for (; i < n4; i += stride){
    float4 v = reinterpret_cast<const float4*>(in)[i];
    reinterpret_cast<u32x4*>(out)[i] =
      (u32x4){ pack2(v.x), pack2(v.y), pack2(v.z), pack2(v.w) };
  }
}

// ---------------------------------------------------------------------------
// 256x256-tile GEMM on pre-packed split-bf16.
// C[m][n] = sum_k A[m][2K]*B[n][2K] via 16x16x32 bf16 MFMA.
// 8 waves (2Mx4N), BK=64 bf16 (=32 u32 =128B) per K-tile, double-buffered
// 128KB LDS, 4 phases/K-tile, counted vmcnt(4), T2 both-sides swizzle,
// T5 setprio, XCD column-chunked swizzle.
// ---------------------------------------------------------------------------
__global__ __launch_bounds__(512, 2)
void gemm_pk8(const u32* __restrict__ A, const u32* __restrict__ B,
              float* __restrict__ C, int M, int N, int K)  // K = u32 per row
{
  extern __shared__ char smem[];   // 131072 B: [buf2][ A 32KB | B 32KB ]
  const int tid  = threadIdx.x;
  const int lane = tid & 63;
  const int w    = tid >> 6;       // 0..7
  const int wm = w >> 2, wn = w & 3;
  const int ln = lane & 15, lg = lane >> 4;

  // XCD-bijective swizzle, column-major chunks (each XCD: all bm x few bn)
  const int nbm = M >> 8, nbn = N >> 8;
  const int nwg = nbm * nbn;
  const int swz = (blockIdx.x & 7) * (nwg >> 3) + (blockIdx.x >> 3);
  const int bm = swz % nbm, bn = swz / nbm;

  const size_t rbA = (size_t)K * 4;          // row bytes
  const int lrow  = lane >> 3;               // 0..7
  const int lslot = (lane & 7) ^ (lrow & 7); // pre-swizzled source slot
  const char* As0 = (const char*)A + (size_t)(bm*256 + w*8 + lrow)*rbA + lslot*16;
  const char* Bs0 = (const char*)B + (size_t)(bn*256 + w*8 + lrow)*rbA + lslot*16;

  auto stA = [&](int buf, int t) {
    const char* s = As0 + ((size_t)t << 7);
    char* d = smem + buf*65536 + w*1024;
    gload16(s,            d);
    gload16(s +  64*rbA,  d + 8192);
    gload16(s + 128*rbA,  d + 16384);
    gload16(s + 192*rbA,  d + 24576);
  };
  auto stB = [&](int buf, int t) {
    const char* s = Bs0 + ((size_t)t << 7);
    char* d = smem + buf*65536 + 32768 + w*1024;
    gload16(s,            d);
    gload16(s +  64*rbA,  d + 8192);
    gload16(s + 128*rbA,  d + 16384);
    gload16(s + 192*rbA,  d + 24576);
  };

  f32x4 z = {0.f,0.f,0.f,0.f};
  f32x4 acc[8][4];
  #pragma unroll
  for (int i=0;i<8;i++){
    #pragma unroll
    for (int j=0;j<4;j++) acc[i][j] = z;
  }

  const int nt = K >> 5;           // K-tiles of 32 u32 (=64 bf16)
  // prologue: tile0 -> buf0 fully; B(1) -> buf1 (early, gets long cover)
  stA(0, 0); stB(0, 0);
  if (nt > 1) { stB(1, 1);
    asm volatile("s_waitcnt vmcnt(4)" ::: "memory");
  } else {
    asm volatile("s_waitcnt vmcnt(0)" ::: "memory");
  }
  __builtin_amdgcn_s_barrier();
  asm volatile("" ::: "memory");

  const int aoff  = wm*16384;
  const int boff  = 32768 + (wn>>1)*16384;
  const int brow0 = (wn&1)*64;
  const int lx7   = ln & 7;

  for (int t = 0; t < nt; ++t){
    const int cur = t & 1;
    const char* bufc = smem + cur*65536;

    // ---- phase 0: all B frags + A quad 0; stage A(t+1) -> other buf ----
    FragU bfr[4][2];
    #pragma unroll
    for (int ni=0; ni<4; ni++){
      const int rofs = boff + (brow0 + ni*16 + ln)*128;
      #pragma unroll
      for (int ks=0; ks<2; ks++)
        bfr[ni][ks].q = *reinterpret_cast<const u32x4*>(bufc + rofs + (((ks*4+lg)^lx7)<<4));
    }
    FragU a0[2][2];
    #pragma unroll
    for (int mm=0; mm<2; mm++){
      const int rofs = aoff + (mm*16 + ln)*128;
      #pragma unroll
      for (int ks=0; ks<2; ks++)
        a0[mm][ks].q = *reinterpret_cast<const u32x4*>(bufc + rofs + (((ks*4+lg)^lx7)<<4));
    }
    if (t+1 < nt) stA(cur^1, t+1);
    __builtin_amdgcn_s_barrier();
    __builtin_amdgcn_s_setprio(1);
    #pragma unroll
    for (int ks=0; ks<2; ks++){
      #pragma unroll
      for (int mm=0; mm<2; mm++){
        #pragma unroll
        for (int ni=0; ni<4; ni++)
          acc[mm][ni] = __builtin_amdgcn_mfma_f32_16x16x32_bf16(a0[mm][ks].v, bfr[ni][ks].v, acc[mm][ni], 0,0,0);
      }
    }
    __builtin_amdgcn_s_setprio(0);
    // fence: all waves' B-frag LDS reads complete before crossing this barrier,
    // which licenses staging B(t+2) into this buffer's B region next phase.
    asm volatile("s_waitcnt lgkmcnt(0)" ::: "memory");
    __builtin_amdgcn_s_barrier();

    // ---- phases 1..3: A quads; phase 1 stages B(t+2) -> B[cur] ----
    #pragma unroll
    for (int q2=1; q2<4; q2++){
      FragU aq[2][2];
      #pragma unroll
      for (int mm=0; mm<2; mm++){
        const int rofs = aoff + ((q2*2+mm)*16 + ln)*128;
        #pragma unroll
        for (int ks=0; ks<2; ks++)
          aq[mm][ks].q = *reinterpret_cast<const u32x4*>(bufc + rofs + (((ks*4+lg)^lx7)<<4));
      }
      if (q2 == 1 && t+2 < nt) stB(cur, t+2);
      __builtin_amdgcn_s_barrier();
      __builtin_amdgcn_s_setprio(1);
      #pragma unroll
      for (int ks=0; ks<2; ks++){
        #pragma unroll
        for (int mm=0; mm<2; mm++){
          #pragma unroll
          for (int ni=0; ni<4; ni++)
            acc[q2*2+mm][ni] = __builtin_amdgcn_mfma_f32_16x16x32_bf16(aq[mm][ks].v, bfr[ni][ks].v, acc[q2*2+mm][ni], 0,0,0);
        }
      }
      __builtin_amdgcn_s_setprio(0);
      if (q2 < 3) __builtin_amdgcn_s_barrier();
    }
    // ---- iteration boundary: counted wait (never 0 mid-loop) ----
    if (t+1 < nt){
      if (t+2 < nt) asm volatile("s_waitcnt vmcnt(4)" ::: "memory");
      else          asm volatile("s_waitcnt vmcnt(0)" ::: "memory");
    }
    __builtin_amdgcn_s_barrier();
    asm volatile("" ::: "memory");
  }

  #pragma unroll
  for (int mi=0; mi<8; mi++){
    #pragma unroll
    for (int ni=0; ni<4; ni++){
      const int row0 = bm*256 + wm*128 + mi*16 + lg*4;
      const int col  = bn*256 + wn*64  + ni*16 + ln;
      #pragma unroll
      for (int r=0; r<4; r++)
        C[(size_t)(row0+r)*N + col] = acc[mi][ni][r];
    }
  }
}

// ---------------------------------------------------------------------------
// Gather old paged cache into contiguous PACKED ws buffers.
// k_all  : u32 [B][HKV][1024][128]   v_allT : u32 [B][HKV][128][1024]
// ---------------------------------------------------------------------------
__global__ __launch_bounds__(256)
void copy_cache(const float* __restrict__ k_cache, const float* __restrict__ v_cache,
                const int* __restrict__ page_table,
                u32* __restrict__ k_all, u32* __restrict__ v_allT)
{
  __shared__ float tb[32][129];
  const int id = blockIdx.x;
  const int jt = id & 31, h = (id>>5)&7, b = id>>8;
  const int tid = threadIdx.x;
  const int j0 = jt*32;
  {
    int r = tid>>3, c = tid&7;
    int j = j0 + r;
    int page = page_table[b*64 + (j>>4)];
    int slot = j & 15;
    const float* ks = k_cache + (size_t)((page*16 + slot)*8 + h)*128;
    const float* vs = v_cache + (size_t)((page*16 + slot)*8 + h)*128;
    u32* kd = k_all + ((size_t)(b*8+h)*1024 + j)*128;
    #pragma unroll
    for (int i=0;i<4;i++){
      int d0 = (c + 8*i)*4;
      float4 k4 = *reinterpret_cast<const float4*>(ks + d0);
      *reinterpret_cast<u32x4*>(kd + d0) =
        (u32x4){ pack2(k4.x), pack2(k4.y), pack2(k4.z), pack2(k4.w) };
      float4 v4 = *reinterpret_cast<const float4*>(vs + d0);
      tb[r][d0+0]=v4.x; tb[r][d0+1]=v4.y; tb[r][d0+2]=v4.z; tb[r][d0+3]=v4.w;
    }
  }
  __syncthreads();
  {
    int dout = tid>>1, jh = tid&1;
    u32* vd = v_allT + ((size_t)(b*8+h)*128 + dout)*1024 + j0 + jh*16;
    #pragma unroll
    for (int i=0;i<4;i++){
      u32x4 o;
      o.x = pack2(tb[jh*16 + i*4 + 0][dout]);
      o.y = pack2(tb[jh*16 + i*4 + 1][dout]);
      o.z = pack2(tb[jh*16 + i*4 + 2][dout]);
      o.w = pack2(tb[jh*16 + i*4 + 3][dout]);
      *reinterpret_cast<u32x4*>(vd + i*4) = o;
    }
  }
}

// ---------------------------------------------------------------------------
// Per-head RMSNorm + partial RoPE + scatter new K/V (packed) into k_all/v_allT.
// ---------------------------------------------------------------------------
__global__ __launch_bounds__(256)
void norm_rope_scatter(float* __restrict__ qkv, const float* __restrict__ cosT,
                       const float* __restrict__ sinT, const int* __restrict__ positions,
                       const int* __restrict__ cache_seqlens,
                       const float* __restrict__ qw, const float* __restrict__ kw,
                       u32* __restrict__ k_all, u32* __restrict__ v_allT)
{
  const int t = blockIdx.x;
  const int lane = threadIdx.x & 63;
  const int w = threadIdx.x >> 6;
  const int b = t >> 9;        // QL = 512
  const int q = t & 511;
  const int pos  = positions[t];
  const int cpos = cache_seqlens[b] + q;
  for (int it=0; it<12; ++it){
    int h = it*4 + w;          // 0..47
    float* xp = qkv + (size_t)t*6144 + h*128 + 2*lane;
    float2 x = *reinterpret_cast<const float2*>(xp);
    if (h < 40){               // q + k heads get RMSNorm + RoPE
      float ss = x.x*x.x + x.y*x.y;
      #pragma unroll
      for (int mk=1; mk<64; mk<<=1) ss += __shfl_xor(ss, mk);
      float var = ss*(1.0f/128.0f) + 1e-6f;
      float rq = rsqrtf(var);
      rq = rq*(1.5f - 0.5f*var*rq*rq);   // Newton refine
      const float* wt = (h<32) ? qw : kw;
      x.x *= rq*wt[2*lane]; x.y *= rq*wt[2*lane+1];
      float px = __shfl_xor(x.x, 16);
      float py = __shfl_xor(x.y, 16);
      if (lane < 32){
        int ci = pos*32 + 2*(lane&15);
        float2 cc = *reinterpret_cast<const float2*>(cosT + ci);
        float2 sc = *reinterpret_cast<const float2*>(sinT + ci);
        if (lane < 16){ x.x = x.x*cc.x - px*sc.x; x.y = x.y*cc.y - py*sc.y; }
        else          { x.x = x.x*cc.x + px*sc.x; x.y = x.y*cc.y + py*sc.y; }
      }
    }
    if (h < 32){
      *reinterpret_cast<float2*>(xp) = x;   // q back in place (fp32)
    } else if (h < 40){
      u32* kp = k_all + ((size_t)(b*8 + (h-32))*1024 + cpos)*128 + 2*lane;
      kp[0] = pack2(x.x); kp[1] = pack2(x.y);
    } else {
      u32* vp = v_allT + ((size_t)(b*8 + (h-40))*128 + 2*lane)*1024 + cpos;
      vp[0]    = pack2(x.x);
      vp[1024] = pack2(x.y);
    }
  }
}

// ---------------------------------------------------------------------------
// Fused GQA causal attention.  Block = (b, kv-head, g, 64-row q tile),
// 4 waves x 16 q-rows. KV tiles of 32, split-bf16 MFMA, fp32 online softmax.
// K/V come pre-packed; output written PACKED for the O-proj GEMM.
// ---------------------------------------------------------------------------
__global__ __launch_bounds__(256)
void attn_fused(const float* __restrict__ qkv, const u32* __restrict__ k_all,
                const u32* __restrict__ v_allT, const int* __restrict__ cache_seqlens,
                u32* __restrict__ attnO)
{
  __shared__ u16 Ks[32*256];     // [kv][k'=2d+s]  (swizzled)
  __shared__ u16 Vs[128*64];     // [d][k''=2kv+s] (swizzled)
  __shared__ float Pl[4*16*32];  // per-wave P tile (swizzled)
  const int tid = threadIdx.x, lane = tid&63, w = tid>>6;
  const int ln = lane&15, lg = lane>>4;
  const int id = blockIdx.x;
  const int qt = id & 7, g = (id>>3)&3, kvh = (id>>5)&7, b = id>>8;
  const int cs = cache_seqlens[b];
  const int h  = kvh*4 + g;
  const int q0 = qt*64 + w*16;
  const float SCALE = 0.08838834764831845f;  // 1/sqrt(128)
  f32x4 z = {0.f,0.f,0.f,0.f};

  FragU qf[8];
  {
    const float* qp = qkv + (size_t)(b*512 + q0 + ln)*6144 + h*128;
    #pragma unroll
    for (int ks=0; ks<8; ks++){
      int d0 = ks*16 + lg*4;
      float4 v4 = *reinterpret_cast<const float4*>(qp + d0);
      qf[ks].q = (u32x4){ pack2(v4.x*SCALE), pack2(v4.y*SCALE),
                          pack2(v4.z*SCALE), pack2(v4.w*SCALE) };
    }
  }
  f32x4 O[8];
  #pragma unroll
  for (int i=0;i<8;i++) O[i] = z;
  float m[4] = {-1e30f,-1e30f,-1e30f,-1e30f};
  float l[4] = {0.f,0.f,0.f,0.f};
  const int prow0 = cs + q0 + lg*4;
  const int ntiles = (cs + qt*64 + 64 + 31) >> 5;
  const u32* kbase = k_all  + (size_t)(b*8+kvh)*1024*128;
  const u32* vbase = v_allT + (size_t)(b*8+kvh)*128*1024;

  for (int tile=0; tile<ntiles; ++tile){
    const int kv0 = tile*32;
    __syncthreads();
    {   // stage K tile (32 kv x 128 d), already packed
      int r = tid>>3;
      const u32* kp = kbase + (size_t)(kv0 + r)*128;
      #pragma unroll
      for (int c2=0;c2<4;c2++){
        int d0 = ((tid&7) + 8*c2)*4;
        u32x4 pk = *reinterpret_cast<const u32x4*>(kp + d0);
        *reinterpret_cast<u32x4*>(&Ks[(r*256 + d0*2) ^ ((r&7)<<3)]) = pk;
      }
    }
    {   // stage V tile (transposed source), already packed
      int dr = tid>>1;
      const u32* vp = vbase + (size_t)dr*1024 + kv0;
      #pragma unroll
      for (int c2=0;c2<4;c2++){
        int kl0 = ((tid&1)*4 + c2)*4;
        u32x4 pv4 = *reinterpret_cast<const u32x4*>(vp + kl0);
        *reinterpret_cast<u32x4*>(&Vs[(dr*64 + kl0*2) ^ ((dr&7)<<3)]) = pv4;
      }
    }
    __syncthreads();
    // S = Q K^T (split-bf16 over K'=256)
    f32x4 s[2]; s[0]=z; s[1]=z;
    #pragma unroll
    for (int ks=0; ks<8; ks++){
      int kb = ks*32 + lg*8;
      #pragma unroll
      for (int n=0;n<2;n++){
        int kr = n*16 + ln;
        FragU kf;
        kf.q = *reinterpret_cast<const u32x4*>(&Ks[(kr*256 + kb) ^ ((kr&7)<<3)]);
        s[n] = __builtin_amdgcn_mfma_f32_16x16x32_bf16(qf[ks].v, kf.v, s[n], 0,0,0);
      }
    }
    // online softmax (rows = lg*4+r)
    float mx[4];
    #pragma unroll
    for (int r=0;r<4;r++){
      int pr = prow0 + r;
      float a0 = (kv0 + ln      <= pr) ? s[0][r] : -1e30f;
      float a1 = (kv0 + 16 + ln <= pr) ? s[1][r] : -1e30f;
      mx[r] = fmaxf(a0, a1);
    }
    #pragma unroll
    for (int off=1; off<16; off<<=1){
      #pragma unroll
      for (int r=0;r<4;r++) mx[r] = fmaxf(mx[r], __shfl_xor(mx[r], off));
    }
    float corr[4];
    #pragma unroll
    for (int r=0;r<4;r++){
      float mn = fmaxf(m[r], mx[r]);
      corr[r] = __expf(m[r] - mn);
      m[r] = mn;
    }
    float pv[2][4], ps[4] = {0.f,0.f,0.f,0.f};
    #pragma unroll
    for (int n=0;n<2;n++){
      #pragma unroll
      for (int r=0;r<4;r++){
        bool ok = (kv0 + n*16 + ln) <= (prow0 + r);
        float p = ok ? __expf(s[n][r] - m[r]) : 0.f;
        pv[n][r] = p;
        ps[r] += p;
      }
    }
    #pragma unroll
    for (int off=1; off<16; off<<=1){
      #pragma unroll
      for (int r=0;r<4;r++) ps[r] += __shfl_xor(ps[r], off);
    }
    #pragma unroll
    for (int r=0;r<4;r++) l[r] = l[r]*corr[r] + ps[r];
    #pragma unroll
    for (int nf=0; nf<8; nf++){
      #pragma unroll
      for (int r=0;r<4;r++) O[nf][r] = O[nf][r]*corr[r];
    }
    // P -> per-wave LDS (swizzled), then build duplicated hi/lo A-frags
    #pragma unroll
    for (int n=0;n<2;n++){
      #pragma unroll
      for (int r=0;r<4;r++){
        int row = lg*4 + r;
        Pl[w*512 + ((row*32 + n*16 + ln) ^ ((row&7)<<2))] = pv[n][r];
      }
    }
    FragU pah[2], pal[2];
    #pragma unroll
    for (int ks2=0; ks2<2; ks2++){
      int fi = (ln*32 + ks2*16 + lg*4) ^ ((ln&7)<<2);
      float4 pp = *reinterpret_cast<const float4*>(&Pl[w*512 + fi]);
      float parr[4] = {pp.x, pp.y, pp.z, pp.w};
      #pragma unroll
      for (int i=0;i<4;i++){
        u16 hh = bfhi(parr[i]);
        u16 ll = bfhi(parr[i] - bff(hh));
        pah[ks2].us[2*i] = hh; pah[ks2].us[2*i+1] = hh;
        pal[ks2].us[2*i] = ll; pal[ks2].us[2*i+1] = ll;
      }
    }
    // O += (Ph+Pl) x (Vh+Vl)
    #pragma unroll
    for (int nf=0; nf<8; nf++){
      int dr = nf*16 + ln;
      #pragma unroll
      for (int ks2=0; ks2<2; ks2++){
        FragU vf;
        vf.q = *reinterpret_cast<const u32x4*>(&Vs[(dr*64 + ks2*32 + lg*8) ^ ((dr&7)<<3)]);
        O[nf] = __builtin_amdgcn_mfma_f32_16x16x32_bf16(pah[ks2].v, vf.v, O[nf], 0,0,0);
        O[nf] = __builtin_amdgcn_mfma_f32_16x16x32_bf16(pal[ks2].v, vf.v, O[nf], 0,0,0);
      }
    }
  }
  float il[4];
  #pragma unroll
  for (int r=0;r<4;r++) il[r] = 1.0f / l[r];
  u32* op = attnO + (size_t)(b*512 + q0 + lg*4)*4096 + h*128 + ln;
  #pragma unroll
  for (int nf=0; nf<8; nf++){
    #pragma unroll
    for (int r=0;r<4;r++)
      op[(size_t)r*4096 + nf*16] = pack2(O[nf][r] * il[r]);
  }
}

// ---------------------------------------------------------------------------
extern "C" void kernel_launch(void* const* d_in, const int* in_sizes, int n_in,
                              void* d_out, int out_size, void* d_ws, size_t ws_size,
                              hipStream_t stream) {
  const float* hidden    = (const float*)d_in[0];
  const float* cosT      = (const float*)d_in[1];
  const float* sinT      = (const float*)d_in[2];
  const int*   positions = (const int*)  d_in[3];
  const float* k_cache   = (const float*)d_in[4];
  const float* v_cache   = (const float*)d_in[5];
  const int*   page_tab  = (const int*)  d_in[6];
  const int*   cache_sl  = (const int*)  d_in[7];
  const float* qkv_w     = (const float*)d_in[9];
  const float* o_w       = (const float*)d_in[10];
  const float* qnw       = (const float*)d_in[11];
  const float* knw       = (const float*)d_in[12];
  float* out = (float*)d_out;

  u32* ws      = (u32*)d_ws;
  float* qkv   = (float*)ws;                // 2048*6144        = 12582912
  u32* k_all   = ws      + 12582912;        // 4*8*1024*128     =  4194304
  u32* v_allT  = k_all   + 4194304;         //                  =  4194304
  u32* attnPk  = v_allT  + 4194304;         // 2048*4096        =  8388608
  u32* hidPk   = attnPk  + 8388608;         // 2048*4096        =  8388608
  u32* qkvwPk  = hidPk   + 8388608;         // 6144*4096        = 25165824
  u32* owPk    = qkvwPk  + 25165824;        // 4096*4096        = 16777216
  (void)in_sizes; (void)n_in; (void)out_size; (void)ws_size;

  (void)hipFuncSetAttribute(reinterpret_cast<const void*>(gemm_pk8),
                            hipFuncAttributeMaxDynamicSharedMemorySize, 131072);

  hipLaunchKernelGGL(split_pack, dim3(1024), dim3(256), 0, stream,
                     hidden, hidPk, 2097152);
  hipLaunchKernelGGL(split_pack, dim3(1024), dim3(256), 0, stream,
                     qkv_w, qkvwPk, 6291456);
  hipLaunchKernelGGL(split_pack, dim3(1024), dim3(256), 0, stream,
                     o_w, owPk, 4194304);
  hipLaunchKernelGGL(copy_cache, dim3(1024), dim3(256), 0, stream,
                     k_cache, v_cache, page_tab, k_all, v_allT);
  hipLaunchKernelGGL(gemm_pk8, dim3(192), dim3(512), 131072, stream,
                     hidPk, qkvwPk, qkv, 2048, 6144, 4096);
  hipLaunchKernelGGL(norm_rope_scatter, dim3(2048), dim3(256), 0, stream,
                     qkv, cosT, sinT, positions, cache_sl, qnw, knw, k_all, v_allT);
  hipLaunchKernelGGL(attn_fused, dim3(1024), dim3(256), 0, stream,
                     qkv, k_all, v_allT, cache_sl, attnPk);
  hipLaunchKernelGGL(gemm_pk8, dim3(128), dim3(512), 131072, stream,
                     attnPk, owPk, out, 2048, 4096, 4096);
}

// Round 4
// 669.897 us; speedup vs baseline: 1.3465x; 1.0983x over previous
//
#include <hip/hip_runtime.h>

typedef unsigned int   u32;
typedef unsigned short u16;

typedef float  f32x4  __attribute__((ext_vector_type(4)));
typedef u32    u32x4  __attribute__((ext_vector_type(4)));
typedef __bf16 bf16x8 __attribute__((ext_vector_type(8)));

union FragU { u16 us[8]; u32x4 q; bf16x8 v; };

__device__ __forceinline__ u32 f2u(float x){ union{float f;u32 u;}c; c.f=x; return c.u; }
__device__ __forceinline__ float u2f(u32 u){ union{float f;u32 u;}c; c.u=u; return c.f; }
__device__ __forceinline__ u16 bfhi(float x){ u32 u=f2u(x); return (u16)((u + 0x7fffu + ((u>>16)&1u))>>16); }
__device__ __forceinline__ float bff(u16 h){ return u2f(((u32)h)<<16); }
// fp32 -> (hi,lo) bf16 pair packed in one u32 (low half = hi part)
__device__ __forceinline__ u32 pack2(float x){
  u16 h = bfhi(x);
  u16 l = bfhi(x - bff(h));
  return (u32)h | ((u32)l << 16);
}

__device__ __forceinline__ void gload16(const void* g, void* l){
  __builtin_amdgcn_global_load_lds(
      (const __attribute__((address_space(1))) unsigned int*)g,
      (__attribute__((address_space(3))) unsigned int*)l, 16, 0, 0);
}

// ---------------------------------------------------------------------------
// Elementwise fp32 -> packed split-bf16 (u32 per element).
// ---------------------------------------------------------------------------
__global__ __launch_bounds__(256)
void split_pack(const float* __restrict__ in, u32* __restrict__ out, int n4)
{
  int i = blockIdx.x*256 + threadIdx.x;
  const int stride = gridDim.x*256;
  for (; i < n4; i += stride){
    float4 v = reinterpret_cast<const float4*>(in)[i];
    reinterpret_cast<u32x4*>(out)[i] =
      (u32x4){ pack2(v.x), pack2(v.y), pack2(v.z), pack2(v.w) };
  }
}

// ---------------------------------------------------------------------------
// 256x256-tile GEMM on pre-packed split-bf16.
// 8 waves (2Mx4N), BK=64 bf16 per K-tile, double-buffered 128KB LDS,
// 4 phases/K-tile, counted vmcnt(4), both-sides swizzle, setprio,
// XCD column-chunked swizzle.
// ---------------------------------------------------------------------------
__global__ __launch_bounds__(512, 2)
void gemm_pk8(const u32* __restrict__ A, const u32* __restrict__ B,
              float* __restrict__ C, int M, int N, int K)  // K = u32 per row
{
  extern __shared__ char smem[];   // 131072 B: [buf2][ A 32KB | B 32KB ]
  const int tid  = threadIdx.x;
  const int lane = tid & 63;
  const int w    = tid >> 6;       // 0..7
  const int wm = w >> 2, wn = w & 3;
  const int ln = lane & 15, lg = lane >> 4;

  // XCD-bijective swizzle, column-major chunks (each XCD: all bm x few bn)
  const int nbm = M >> 8, nbn = N >> 8;
  const int nwg = nbm * nbn;
  const int swz = (blockIdx.x & 7) * (nwg >> 3) + (blockIdx.x >> 3);
  const int bm = swz % nbm, bn = swz / nbm;

  const size_t rbA = (size_t)K * 4;          // row bytes
  const int lrow  = lane >> 3;               // 0..7
  const int lslot = (lane & 7) ^ (lrow & 7); // pre-swizzled source slot
  const char* As0 = (const char*)A + (size_t)(bm*256 + w*8 + lrow)*rbA + lslot*16;
  const char* Bs0 = (const char*)B + (size_t)(bn*256 + w*8 + lrow)*rbA + lslot*16;

  auto stA = [&](int buf, int t) {
    const char* s = As0 + ((size_t)t << 7);
    char* d = smem + buf*65536 + w*1024;
    gload16(s,            d);
    gload16(s +  64*rbA,  d + 8192);
    gload16(s + 128*rbA,  d + 16384);
    gload16(s + 192*rbA,  d + 24576);
  };
  auto stB = [&](int buf, int t) {
    const char* s = Bs0 + ((size_t)t << 7);
    char* d = smem + buf*65536 + 32768 + w*1024;
    gload16(s,            d);
    gload16(s +  64*rbA,  d + 8192);
    gload16(s + 128*rbA,  d + 16384);
    gload16(s + 192*rbA,  d + 24576);
  };

  f32x4 z = {0.f,0.f,0.f,0.f};
  f32x4 acc[8][4];
  #pragma unroll
  for (int i=0;i<8;i++){
    #pragma unroll
    for (int j=0;j<4;j++) acc[i][j] = z;
  }

  const int nt = K >> 5;           // K-tiles of 32 u32 (=64 bf16)
  // prologue: tile0 -> buf0 fully; B(1) -> buf1 (early, gets long cover)
  stA(0, 0); stB(0, 0);
  if (nt > 1) { stB(1, 1);
    asm volatile("s_waitcnt vmcnt(4)" ::: "memory");
  } else {
    asm volatile("s_waitcnt vmcnt(0)" ::: "memory");
  }
  __builtin_amdgcn_s_barrier();
  asm volatile("" ::: "memory");

  const int aoff  = wm*16384;
  const int boff  = 32768 + (wn>>1)*16384;
  const int brow0 = (wn&1)*64;
  const int lx7   = ln & 7;

  for (int t = 0; t < nt; ++t){
    const int cur = t & 1;
    const char* bufc = smem + cur*65536;

    // ---- phase 0: all B frags + A quad 0; stage A(t+1) -> other buf ----
    FragU bfr[4][2];
    #pragma unroll
    for (int ni=0; ni<4; ni++){
      const int rofs = boff + (brow0 + ni*16 + ln)*128;
      #pragma unroll
      for (int ks=0; ks<2; ks++)
        bfr[ni][ks].q = *reinterpret_cast<const u32x4*>(bufc + rofs + (((ks*4+lg)^lx7)<<4));
    }
    FragU a0[2][2];
    #pragma unroll
    for (int mm=0; mm<2; mm++){
      const int rofs = aoff + (mm*16 + ln)*128;
      #pragma unroll
      for (int ks=0; ks<2; ks++)
        a0[mm][ks].q = *reinterpret_cast<const u32x4*>(bufc + rofs + (((ks*4+lg)^lx7)<<4));
    }
    if (t+1 < nt) stA(cur^1, t+1);
    __builtin_amdgcn_s_barrier();
    __builtin_amdgcn_s_setprio(1);
    #pragma unroll
    for (int ks=0; ks<2; ks++){
      #pragma unroll
      for (int mm=0; mm<2; mm++){
        #pragma unroll
        for (int ni=0; ni<4; ni++)
          acc[mm][ni] = __builtin_amdgcn_mfma_f32_16x16x32_bf16(a0[mm][ks].v, bfr[ni][ks].v, acc[mm][ni], 0,0,0);
      }
    }
    __builtin_amdgcn_s_setprio(0);
    // fence: all waves' B-frag LDS reads complete before crossing this barrier,
    // which licenses staging B(t+2) into this buffer's B region next phase.
    asm volatile("s_waitcnt lgkmcnt(0)" ::: "memory");
    __builtin_amdgcn_s_barrier();

    // ---- phases 1..3: A quads; phase 1 stages B(t+2) -> B[cur] ----
    #pragma unroll
    for (int q2=1; q2<4; q2++){
      FragU aq[2][2];
      #pragma unroll
      for (int mm=0; mm<2; mm++){
        const int rofs = aoff + ((q2*2+mm)*16 + ln)*128;
        #pragma unroll
        for (int ks=0; ks<2; ks++)
          aq[mm][ks].q = *reinterpret_cast<const u32x4*>(bufc + rofs + (((ks*4+lg)^lx7)<<4));
      }
      if (q2 == 1 && t+2 < nt) stB(cur, t+2);
      __builtin_amdgcn_s_barrier();
      __builtin_amdgcn_s_setprio(1);
      #pragma unroll
      for (int ks=0; ks<2; ks++){
        #pragma unroll
        for (int mm=0; mm<2; mm++){
          #pragma unroll
          for (int ni=0; ni<4; ni++)
            acc[q2*2+mm][ni] = __builtin_amdgcn_mfma_f32_16x16x32_bf16(aq[mm][ks].v, bfr[ni][ks].v, acc[q2*2+mm][ni], 0,0,0);
        }
      }
      __builtin_amdgcn_s_setprio(0);
      if (q2 < 3) __builtin_amdgcn_s_barrier();
    }
    // ---- iteration boundary: counted wait (never 0 mid-loop) ----
    if (t+1 < nt){
      if (t+2 < nt) asm volatile("s_waitcnt vmcnt(4)" ::: "memory");
      else          asm volatile("s_waitcnt vmcnt(0)" ::: "memory");
    }
    __builtin_amdgcn_s_barrier();
    asm volatile("" ::: "memory");
  }

  #pragma unroll
  for (int mi=0; mi<8; mi++){
    #pragma unroll
    for (int ni=0; ni<4; ni++){
      const int row0 = bm*256 + wm*128 + mi*16 + lg*4;
      const int col  = bn*256 + wn*64  + ni*16 + ln;
      #pragma unroll
      for (int r=0; r<4; r++)
        C[(size_t)(row0+r)*N + col] = acc[mi][ni][r];
    }
  }
}

// ---------------------------------------------------------------------------
// 128x256-tile variant (full-CU-coverage shape for M=2048,N=4096: 256 blocks).
// Same schedule; wave = 64x64, acc[4][4]; A stages 2 loads, B stages 4.
// LDS 96KB = 2 x (A 16KB + B 32KB).
// ---------------------------------------------------------------------------
__global__ __launch_bounds__(512, 2)
void gemm_pk12(const u32* __restrict__ A, const u32* __restrict__ B,
               float* __restrict__ C, int M, int N, int K)  // K = u32 per row
{
  extern __shared__ char smem[];   // 98304 B: [buf2][ A 16KB | B 32KB ]
  const int tid  = threadIdx.x;
  const int lane = tid & 63;
  const int w    = tid >> 6;       // 0..7
  const int wm = w >> 2, wn = w & 3;
  const int ln = lane & 15, lg = lane >> 4;

  const int nbm = M >> 7, nbn = N >> 8;
  const int nwg = nbm * nbn;
  const int swz = (blockIdx.x & 7) * (nwg >> 3) + (blockIdx.x >> 3);
  const int bm = swz % nbm, bn = swz / nbm;

  const size_t rbA = (size_t)K * 4;          // row bytes
  const int lrow  = lane >> 3;               // 0..7
  const int lslot = (lane & 7) ^ (lrow & 7); // pre-swizzled source slot
  const char* As0 = (const char*)A + (size_t)(bm*128 + w*8 + lrow)*rbA + lslot*16;
  const char* Bs0 = (const char*)B + (size_t)(bn*256 + w*8 + lrow)*rbA + lslot*16;

  auto stA = [&](int buf, int t) {
    const char* s = As0 + ((size_t)t << 7);
    char* d = smem + buf*49152 + w*1024;
    gload16(s,            d);
    gload16(s +  64*rbA,  d + 8192);
  };
  auto stB = [&](int buf, int t) {
    const char* s = Bs0 + ((size_t)t << 7);
    char* d = smem + buf*49152 + 16384 + w*1024;
    gload16(s,            d);
    gload16(s +  64*rbA,  d + 8192);
    gload16(s + 128*rbA,  d + 16384);
    gload16(s + 192*rbA,  d + 24576);
  };

  f32x4 z = {0.f,0.f,0.f,0.f};
  f32x4 acc[4][4];
  #pragma unroll
  for (int i=0;i<4;i++){
    #pragma unroll
    for (int j=0;j<4;j++) acc[i][j] = z;
  }

  const int nt = K >> 5;           // K-tiles of 32 u32 (=64 bf16)
  stA(0, 0); stB(0, 0);            // 6 loads
  if (nt > 1) { stB(1, 1);         // +4
    asm volatile("s_waitcnt vmcnt(4)" ::: "memory");   // tile0's 6 complete
  } else {
    asm volatile("s_waitcnt vmcnt(0)" ::: "memory");
  }
  __builtin_amdgcn_s_barrier();
  asm volatile("" ::: "memory");

  const int boff0 = 16384;
  const int lx7   = ln & 7;

  for (int t = 0; t < nt; ++t){
    const int cur = t & 1;
    const char* bufc = smem + cur*49152;

    // ---- phase 0: all B frags + A row-frag 0; stage A(t+1) -> other buf ----
    FragU bfr[4][2];
    #pragma unroll
    for (int ni=0; ni<4; ni++){
      const int rofs = boff0 + (wn*64 + ni*16 + ln)*128;
      #pragma unroll
      for (int ks=0; ks<2; ks++)
        bfr[ni][ks].q = *reinterpret_cast<const u32x4*>(bufc + rofs + (((ks*4+lg)^lx7)<<4));
    }
    FragU a0[2];
    {
      const int rofs = (wm*64 + ln)*128;
      #pragma unroll
      for (int ks=0; ks<2; ks++)
        a0[ks].q = *reinterpret_cast<const u32x4*>(bufc + rofs + (((ks*4+lg)^lx7)<<4));
    }
    if (t+1 < nt) stA(cur^1, t+1);
    __builtin_amdgcn_s_barrier();
    __builtin_amdgcn_s_setprio(1);
    #pragma unroll
    for (int ks=0; ks<2; ks++){
      #pragma unroll
      for (int ni=0; ni<4; ni++)
        acc[0][ni] = __builtin_amdgcn_mfma_f32_16x16x32_bf16(a0[ks].v, bfr[ni][ks].v, acc[0][ni], 0,0,0);
    }
    __builtin_amdgcn_s_setprio(0);
    asm volatile("s_waitcnt lgkmcnt(0)" ::: "memory");
    __builtin_amdgcn_s_barrier();

    // ---- phases 1..3: A row-frags; phase 1 stages B(t+2) -> B[cur] ----
    #pragma unroll
    for (int q2=1; q2<4; q2++){
      FragU aq[2];
      {
        const int rofs = (wm*64 + q2*16 + ln)*128;
        #pragma unroll
        for (int ks=0; ks<2; ks++)
          aq[ks].q = *reinterpret_cast<const u32x4*>(bufc + rofs + (((ks*4+lg)^lx7)<<4));
      }
      if (q2 == 1 && t+2 < nt) stB(cur, t+2);
      __builtin_amdgcn_s_barrier();
      __builtin_amdgcn_s_setprio(1);
      #pragma unroll
      for (int ks=0; ks<2; ks++){
        #pragma unroll
        for (int ni=0; ni<4; ni++)
          acc[q2][ni] = __builtin_amdgcn_mfma_f32_16x16x32_bf16(aq[ks].v, bfr[ni][ks].v, acc[q2][ni], 0,0,0);
      }
      __builtin_amdgcn_s_setprio(0);
      if (q2 < 3) __builtin_amdgcn_s_barrier();
    }
    // ---- iteration boundary: counted wait (never 0 mid-loop) ----
    if (t+1 < nt){
      if (t+2 < nt) asm volatile("s_waitcnt vmcnt(4)" ::: "memory");
      else          asm volatile("s_waitcnt vmcnt(0)" ::: "memory");
    }
    __builtin_amdgcn_s_barrier();
    asm volatile("" ::: "memory");
  }

  #pragma unroll
  for (int mi=0; mi<4; mi++){
    #pragma unroll
    for (int ni=0; ni<4; ni++){
      const int row0 = bm*128 + wm*64 + mi*16 + lg*4;
      const int col  = bn*256 + wn*64 + ni*16 + ln;
      #pragma unroll
      for (int r=0; r<4; r++)
        C[(size_t)(row0+r)*N + col] = acc[mi][ni][r];
    }
  }
}

// ---------------------------------------------------------------------------
// Gather old paged cache into contiguous PACKED ws buffers.
// k_all  : u32 [B][HKV][1024][128]   v_allT : u32 [B][HKV][128][1024]
// ---------------------------------------------------------------------------
__global__ __launch_bounds__(256)
void copy_cache(const float* __restrict__ k_cache, const float* __restrict__ v_cache,
                const int* __restrict__ page_table,
                u32* __restrict__ k_all, u32* __restrict__ v_allT)
{
  __shared__ float tb[32][129];
  const int id = blockIdx.x;
  const int jt = id & 31, h = (id>>5)&7, b = id>>8;
  const int tid = threadIdx.x;
  const int j0 = jt*32;
  {
    int r = tid>>3, c = tid&7;
    int j = j0 + r;
    int page = page_table[b*64 + (j>>4)];
    int slot = j & 15;
    const float* ks = k_cache + (size_t)((page*16 + slot)*8 + h)*128;
    const float* vs = v_cache + (size_t)((page*16 + slot)*8 + h)*128;
    u32* kd = k_all + ((size_t)(b*8+h)*1024 + j)*128;
    #pragma unroll
    for (int i=0;i<4;i++){
      int d0 = (c + 8*i)*4;
      float4 k4 = *reinterpret_cast<const float4*>(ks + d0);
      *reinterpret_cast<u32x4*>(kd + d0) =
        (u32x4){ pack2(k4.x), pack2(k4.y), pack2(k4.z), pack2(k4.w) };
      float4 v4 = *reinterpret_cast<const float4*>(vs + d0);
      tb[r][d0+0]=v4.x; tb[r][d0+1]=v4.y; tb[r][d0+2]=v4.z; tb[r][d0+3]=v4.w;
    }
  }
  __syncthreads();
  {
    int dout = tid>>1, jh = tid&1;
    u32* vd = v_allT + ((size_t)(b*8+h)*128 + dout)*1024 + j0 + jh*16;
    #pragma unroll
    for (int i=0;i<4;i++){
      u32x4 o;
      o.x = pack2(tb[jh*16 + i*4 + 0][dout]);
      o.y = pack2(tb[jh*16 + i*4 + 1][dout]);
      o.z = pack2(tb[jh*16 + i*4 + 2][dout]);
      o.w = pack2(tb[jh*16 + i*4 + 3][dout]);
      *reinterpret_cast<u32x4*>(vd + i*4) = o;
    }
  }
}

// ---------------------------------------------------------------------------
// Per-head RMSNorm + partial RoPE + scatter new K/V (packed) into k_all/v_allT.
// ---------------------------------------------------------------------------
__global__ __launch_bounds__(256)
void norm_rope_scatter(float* __restrict__ qkv, const float* __restrict__ cosT,
                       const float* __restrict__ sinT, const int* __restrict__ positions,
                       const int* __restrict__ cache_seqlens,
                       const float* __restrict__ qw, const float* __restrict__ kw,
                       u32* __restrict__ k_all, u32* __restrict__ v_allT)
{
  const int t = blockIdx.x;
  const int lane = threadIdx.x & 63;
  const int w = threadIdx.x >> 6;
  const int b = t >> 9;        // QL = 512
  const int q = t & 511;
  const int pos  = positions[t];
  const int cpos = cache_seqlens[b] + q;
  for (int it=0; it<12; ++it){
    int h = it*4 + w;          // 0..47
    float* xp = qkv + (size_t)t*6144 + h*128 + 2*lane;
    float2 x = *reinterpret_cast<const float2*>(xp);
    if (h < 40){               // q + k heads get RMSNorm + RoPE
      float ss = x.x*x.x + x.y*x.y;
      #pragma unroll
      for (int mk=1; mk<64; mk<<=1) ss += __shfl_xor(ss, mk);
      float var = ss*(1.0f/128.0f) + 1e-6f;
      float rq = rsqrtf(var);
      rq = rq*(1.5f - 0.5f*var*rq*rq);   // Newton refine
      const float* wt = (h<32) ? qw : kw;
      x.x *= rq*wt[2*lane]; x.y *= rq*wt[2*lane+1];
      float px = __shfl_xor(x.x, 16);
      float py = __shfl_xor(x.y, 16);
      if (lane < 32){
        int ci = pos*32 + 2*(lane&15);
        float2 cc = *reinterpret_cast<const float2*>(cosT + ci);
        float2 sc = *reinterpret_cast<const float2*>(sinT + ci);
        if (lane < 16){ x.x = x.x*cc.x - px*sc.x; x.y = x.y*cc.y - py*sc.y; }
        else          { x.x = x.x*cc.x + px*sc.x; x.y = x.y*cc.y + py*sc.y; }
      }
    }
    if (h < 32){
      *reinterpret_cast<float2*>(xp) = x;   // q back in place (fp32)
    } else if (h < 40){
      u32* kp = k_all + ((size_t)(b*8 + (h-32))*1024 + cpos)*128 + 2*lane;
      kp[0] = pack2(x.x); kp[1] = pack2(x.y);
    } else {
      u32* vp = v_allT + ((size_t)(b*8 + (h-40))*128 + 2*lane)*1024 + cpos;
      vp[0]    = pack2(x.x);
      vp[1024] = pack2(x.y);
    }
  }
}

// ---------------------------------------------------------------------------
// Fused GQA causal attention.  Block = (b, kv-head, g, 64-row q tile),
// 4 waves x 16 q-rows. KV tiles of 32, split-bf16 MFMA, fp32 online softmax.
// K/V come pre-packed; output written PACKED for the O-proj GEMM.
// ---------------------------------------------------------------------------
__global__ __launch_bounds__(256)
void attn_fused(const float* __restrict__ qkv, const u32* __restrict__ k_all,
                const u32* __restrict__ v_allT, const int* __restrict__ cache_seqlens,
                u32* __restrict__ attnO)
{
  __shared__ u16 Ks[32*256];     // [kv][k'=2d+s]  (swizzled)
  __shared__ u16 Vs[128*64];     // [d][k''=2kv+s] (swizzled)
  __shared__ float Pl[4*16*32];  // per-wave P tile (swizzled)
  const int tid = threadIdx.x, lane = tid&63, w = tid>>6;
  const int ln = lane&15, lg = lane>>4;
  const int id = blockIdx.x;
  const int qt = id & 7, g = (id>>3)&3, kvh = (id>>5)&7, b = id>>8;
  const int cs = cache_seqlens[b];
  const int h  = kvh*4 + g;
  const int q0 = qt*64 + w*16;
  const float SCALE = 0.08838834764831845f;  // 1/sqrt(128)
  f32x4 z = {0.f,0.f,0.f,0.f};

  FragU qf[8];
  {
    const float* qp = qkv + (size_t)(b*512 + q0 + ln)*6144 + h*128;
    #pragma unroll
    for (int ks=0; ks<8; ks++){
      int d0 = ks*16 + lg*4;
      float4 v4 = *reinterpret_cast<const float4*>(qp + d0);
      qf[ks].q = (u32x4){ pack2(v4.x*SCALE), pack2(v4.y*SCALE),
                          pack2(v4.z*SCALE), pack2(v4.w*SCALE) };
    }
  }
  f32x4 O[8];
  #pragma unroll
  for (int i=0;i<8;i++) O[i] = z;
  float m[4] = {-1e30f,-1e30f,-1e30f,-1e30f};
  float l[4] = {0.f,0.f,0.f,0.f};
  const int prow0 = cs + q0 + lg*4;
  const int ntiles = (cs + qt*64 + 64 + 31) >> 5;
  const u32* kbase = k_all  + (size_t)(b*8+kvh)*1024*128;
  const u32* vbase = v_allT + (size_t)(b*8+kvh)*128*1024;

  for (int tile=0; tile<ntiles; ++tile){
    const int kv0 = tile*32;
    __syncthreads();
    {   // stage K tile (32 kv x 128 d), already packed
      int r = tid>>3;
      const u32* kp = kbase + (size_t)(kv0 + r)*128;
      #pragma unroll
      for (int c2=0;c2<4;c2++){
        int d0 = ((tid&7) + 8*c2)*4;
        u32x4 pk = *reinterpret_cast<const u32x4*>(kp + d0);
        *reinterpret_cast<u32x4*>(&Ks[(r*256 + d0*2) ^ ((r&7)<<3)]) = pk;
      }
    }
    {   // stage V tile (transposed source), already packed
      int dr = tid>>1;
      const u32* vp = vbase + (size_t)dr*1024 + kv0;
      #pragma unroll
      for (int c2=0;c2<4;c2++){
        int kl0 = ((tid&1)*4 + c2)*4;
        u32x4 pv4 = *reinterpret_cast<const u32x4*>(vp + kl0);
        *reinterpret_cast<u32x4*>(&Vs[(dr*64 + kl0*2) ^ ((dr&7)<<3)]) = pv4;
      }
    }
    __syncthreads();
    // S = Q K^T (split-bf16 over K'=256)
    f32x4 s[2]; s[0]=z; s[1]=z;
    #pragma unroll
    for (int ks=0; ks<8; ks++){
      int kb = ks*32 + lg*8;
      #pragma unroll
      for (int n=0;n<2;n++){
        int kr = n*16 + ln;
        FragU kf;
        kf.q = *reinterpret_cast<const u32x4*>(&Ks[(kr*256 + kb) ^ ((kr&7)<<3)]);
        s[n] = __builtin_amdgcn_mfma_f32_16x16x32_bf16(qf[ks].v, kf.v, s[n], 0,0,0);
      }
    }
    // online softmax (rows = lg*4+r)
    float mx[4];
    #pragma unroll
    for (int r=0;r<4;r++){
      int pr = prow0 + r;
      float a0 = (kv0 + ln      <= pr) ? s[0][r] : -1e30f;
      float a1 = (kv0 + 16 + ln <= pr) ? s[1][r] : -1e30f;
      mx[r] = fmaxf(a0, a1);
    }
    #pragma unroll
    for (int off=1; off<16; off<<=1){
      #pragma unroll
      for (int r=0;r<4;r++) mx[r] = fmaxf(mx[r], __shfl_xor(mx[r], off));
    }
    float corr[4];
    #pragma unroll
    for (int r=0;r<4;r++){
      float mn = fmaxf(m[r], mx[r]);
      corr[r] = __expf(m[r] - mn);
      m[r] = mn;
    }
    float pv[2][4], ps[4] = {0.f,0.f,0.f,0.f};
    #pragma unroll
    for (int n=0;n<2;n++){
      #pragma unroll
      for (int r=0;r<4;r++){
        bool ok = (kv0 + n*16 + ln) <= (prow0 + r);
        float p = ok ? __expf(s[n][r] - m[r]) : 0.f;
        pv[n][r] = p;
        ps[r] += p;
      }
    }
    #pragma unroll
    for (int off=1; off<16; off<<=1){
      #pragma unroll
      for (int r=0;r<4;r++) ps[r] += __shfl_xor(ps[r], off);
    }
    #pragma unroll
    for (int r=0;r<4;r++) l[r] = l[r]*corr[r] + ps[r];
    #pragma unroll
    for (int nf=0; nf<8; nf++){
      #pragma unroll
      for (int r=0;r<4;r++) O[nf][r] = O[nf][r]*corr[r];
    }
    // P -> per-wave LDS (swizzled), then build duplicated hi/lo A-frags
    #pragma unroll
    for (int n=0;n<2;n++){
      #pragma unroll
      for (int r=0;r<4;r++){
        int row = lg*4 + r;
        Pl[w*512 + ((row*32 + n*16 + ln) ^ ((row&7)<<2))] = pv[n][r];
      }
    }
    FragU pah[2], pal[2];
    #pragma unroll
    for (int ks2=0; ks2<2; ks2++){
      int fi = (ln*32 + ks2*16 + lg*4) ^ ((ln&7)<<2);
      float4 pp = *reinterpret_cast<const float4*>(&Pl[w*512 + fi]);
      float parr[4] = {pp.x, pp.y, pp.z, pp.w};
      #pragma unroll
      for (int i=0;i<4;i++){
        u16 hh = bfhi(parr[i]);
        u16 ll = bfhi(parr[i] - bff(hh));
        pah[ks2].us[2*i] = hh; pah[ks2].us[2*i+1] = hh;
        pal[ks2].us[2*i] = ll; pal[ks2].us[2*i+1] = ll;
      }
    }
    // O += (Ph+Pl) x (Vh+Vl)
    #pragma unroll
    for (int nf=0; nf<8; nf++){
      int dr = nf*16 + ln;
      #pragma unroll
      for (int ks2=0; ks2<2; ks2++){
        FragU vf;
        vf.q = *reinterpret_cast<const u32x4*>(&Vs[(dr*64 + ks2*32 + lg*8) ^ ((dr&7)<<3)]);
        O[nf] = __builtin_amdgcn_mfma_f32_16x16x32_bf16(pah[ks2].v, vf.v, O[nf], 0,0,0);
        O[nf] = __builtin_amdgcn_mfma_f32_16x16x32_bf16(pal[ks2].v, vf.v, O[nf], 0,0,0);
      }
    }
  }
  float il[4];
  #pragma unroll
  for (int r=0;r<4;r++) il[r] = 1.0f / l[r];
  u32* op = attnO + (size_t)(b*512 + q0 + lg*4)*4096 + h*128 + ln;
  #pragma unroll
  for (int nf=0; nf<8; nf++){
    #pragma unroll
    for (int r=0;r<4;r++)
      op[(size_t)r*4096 + nf*16] = pack2(O[nf][r] * il[r]);
  }
}

// ---------------------------------------------------------------------------
extern "C" void kernel_launch(void* const* d_in, const int* in_sizes, int n_in,
                              void* d_out, int out_size, void* d_ws, size_t ws_size,
                              hipStream_t stream) {
  const float* hidden    = (const float*)d_in[0];
  const float* cosT      = (const float*)d_in[1];
  const float* sinT      = (const float*)d_in[2];
  const int*   positions = (const int*)  d_in[3];
  const float* k_cache   = (const float*)d_in[4];
  const float* v_cache   = (const float*)d_in[5];
  const int*   page_tab  = (const int*)  d_in[6];
  const int*   cache_sl  = (const int*)  d_in[7];
  const float* qkv_w     = (const float*)d_in[9];
  const float* o_w       = (const float*)d_in[10];
  const float* qnw       = (const float*)d_in[11];
  const float* knw       = (const float*)d_in[12];
  float* out = (float*)d_out;

  u32* ws      = (u32*)d_ws;
  float* qkv   = (float*)ws;                // 2048*6144        = 12582912
  u32* k_all   = ws      + 12582912;        // 4*8*1024*128     =  4194304
  u32* v_allT  = k_all   + 4194304;         //                  =  4194304
  u32* attnPk  = v_allT  + 4194304;         // 2048*4096        =  8388608
  u32* hidPk   = attnPk  + 8388608;         // 2048*4096        =  8388608
  u32* qkvwPk  = hidPk   + 8388608;         // 6144*4096        = 25165824
  u32* owPk    = qkvwPk  + 25165824;        // 4096*4096        = 16777216
  (void)in_sizes; (void)n_in; (void)out_size; (void)ws_size;

  (void)hipFuncSetAttribute(reinterpret_cast<const void*>(gemm_pk8),
                            hipFuncAttributeMaxDynamicSharedMemorySize, 131072);
  (void)hipFuncSetAttribute(reinterpret_cast<const void*>(gemm_pk12),
                            hipFuncAttributeMaxDynamicSharedMemorySize, 98304);

  hipLaunchKernelGGL(split_pack, dim3(1024), dim3(256), 0, stream,
                     hidden, hidPk, 2097152);
  hipLaunchKernelGGL(split_pack, dim3(1024), dim3(256), 0, stream,
                     qkv_w, qkvwPk, 6291456);
  hipLaunchKernelGGL(split_pack, dim3(1024), dim3(256), 0, stream,
                     o_w, owPk, 4194304);
  hipLaunchKernelGGL(copy_cache, dim3(1024), dim3(256), 0, stream,
                     k_cache, v_cache, page_tab, k_all, v_allT);
  hipLaunchKernelGGL(gemm_pk8, dim3(192), dim3(512), 131072, stream,
                     hidPk, qkvwPk, qkv, 2048, 6144, 4096);
  hipLaunchKernelGGL(norm_rope_scatter, dim3(2048), dim3(256), 0, stream,
                     qkv, cosT, sinT, positions, cache_sl, qnw, knw, k_all, v_allT);
  hipLaunchKernelGGL(attn_fused, dim3(1024), dim3(256), 0, stream,
                     qkv, k_all, v_allT, cache_sl, attnPk);
  hipLaunchKernelGGL(gemm_pk12, dim3(256), dim3(512), 98304, stream,
                     attnPk, owPk, out, 2048, 4096, 4096);
}

// Round 5
// 623.656 us; speedup vs baseline: 1.4463x; 1.0741x over previous
//
#include <hip/hip_runtime.h>

typedef unsigned int   u32;
typedef unsigned short u16;

typedef float  f32x4  __attribute__((ext_vector_type(4)));
typedef u32    u32x4  __attribute__((ext_vector_type(4)));
typedef __bf16 bf16x8 __attribute__((ext_vector_type(8)));

union FragU { u16 us[8]; u32x4 q; bf16x8 v; };

__device__ __forceinline__ u32 f2u(float x){ union{float f;u32 u;}c; c.f=x; return c.u; }
__device__ __forceinline__ float u2f(u32 u){ union{float f;u32 u;}c; c.u=u; return c.f; }
__device__ __forceinline__ u16 bfhi(float x){ u32 u=f2u(x); return (u16)((u + 0x7fffu + ((u>>16)&1u))>>16); }
__device__ __forceinline__ float bff(u16 h){ return u2f(((u32)h)<<16); }
// fp32 -> (hi,lo) bf16 pair packed in one u32 (low half = hi part)
__device__ __forceinline__ u32 pack2(float x){
  u16 h = bfhi(x);
  u16 l = bfhi(x - bff(h));
  return (u32)h | ((u32)l << 16);
}

__device__ __forceinline__ void gload16(const void* g, void* l){
  __builtin_amdgcn_global_load_lds(
      (const __attribute__((address_space(1))) unsigned int*)g,
      (__attribute__((address_space(3))) unsigned int*)l, 16, 0, 0);
}

// ---------------------------------------------------------------------------
// Elementwise fp32 -> packed split-bf16 (u32 per element).
// ---------------------------------------------------------------------------
__global__ __launch_bounds__(256)
void split_pack(const float* __restrict__ in, u32* __restrict__ out, int n4)
{
  int i = blockIdx.x*256 + threadIdx.x;
  const int stride = gridDim.x*256;
  for (; i < n4; i += stride){
    float4 v = reinterpret_cast<const float4*>(in)[i];
    reinterpret_cast<u32x4*>(out)[i] =
      (u32x4){ pack2(v.x), pack2(v.y), pack2(v.z), pack2(v.w) };
  }
}

// ---------------------------------------------------------------------------
// 256x192-tile GEMM on pre-packed split-bf16 (full-coverage shape for
// M=2048,N=6144 -> 8x32 = 256 blocks).  8 waves (2Mx4N), wave tile 128x48,
// BK=64 bf16, double-buffered 112KB LDS, 2 fat phases/K-tile (24 MFMA each),
// counted vmcnt(3), both-sides swizzle, setprio, XCD column-chunked swizzle.
// ---------------------------------------------------------------------------
__global__ __launch_bounds__(512, 2)
void gemm_pkA(const u32* __restrict__ A, const u32* __restrict__ B,
              float* __restrict__ C, int M, int N, int K)  // K = u32 per row
{
  extern __shared__ char smem[];   // 114688 B: [buf2][ A 32KB | B 24KB ]
  const int tid  = threadIdx.x;
  const int lane = tid & 63;
  const int w    = tid >> 6;       // 0..7
  const int wm = w >> 2, wn = w & 3;
  const int ln = lane & 15, lg = lane >> 4;

  const int nbm = M >> 8;          // 256-row tiles
  const int nbn = N / 192;
  const int nwg = nbm * nbn;
  const int swz = (blockIdx.x & 7) * (nwg >> 3) + (blockIdx.x >> 3);
  const int bm = swz % nbm, bn = swz / nbm;

  const size_t rbA = (size_t)K * 4;          // row bytes
  const int lrow  = lane >> 3;               // 0..7
  const int lslot = (lane & 7) ^ (lrow & 7); // pre-swizzled source slot
  const char* As0 = (const char*)A + (size_t)(bm*256 + w*8 + lrow)*rbA + lslot*16;
  const char* Bs0 = (const char*)B + (size_t)(bn*192 + w*8 + lrow)*rbA + lslot*16;

  auto stA = [&](int buf, int t) {
    const char* s = As0 + ((size_t)t << 7);
    char* d = smem + buf*57344 + w*1024;
    gload16(s,            d);
    gload16(s +  64*rbA,  d + 8192);
    gload16(s + 128*rbA,  d + 16384);
    gload16(s + 192*rbA,  d + 24576);
  };
  auto stB = [&](int buf, int t) {
    const char* s = Bs0 + ((size_t)t << 7);
    char* d = smem + buf*57344 + 32768 + w*1024;
    gload16(s,            d);
    gload16(s +  64*rbA,  d + 8192);
    gload16(s + 128*rbA,  d + 16384);
  };

  f32x4 z = {0.f,0.f,0.f,0.f};
  f32x4 acc[8][3];
  #pragma unroll
  for (int i=0;i<8;i++){
    #pragma unroll
    for (int j=0;j<3;j++) acc[i][j] = z;
  }

  const int nt = K >> 5;           // K-tiles of 32 u32 (=64 bf16)
  stA(0, 0); stB(0, 0);            // 7 loads
  if (nt > 1) { stB(1, 1);         // +3
    asm volatile("s_waitcnt vmcnt(3)" ::: "memory");   // tile0's 7 complete
  } else {
    asm volatile("s_waitcnt vmcnt(0)" ::: "memory");
  }
  __builtin_amdgcn_s_barrier();
  asm volatile("" ::: "memory");

  const int lx7 = ln & 7;

  for (int t = 0; t < nt; ++t){
    const int cur = t & 1;
    const char* bufc = smem + cur*57344;

    // ---- phase 0: all B frags + A m-frags 0..3; stage A(t+1) ----
    FragU bfr[3][2];
    #pragma unroll
    for (int ni=0; ni<3; ni++){
      const int rofs = 32768 + (wn*48 + ni*16 + ln)*128;
      #pragma unroll
      for (int ks=0; ks<2; ks++)
        bfr[ni][ks].q = *reinterpret_cast<const u32x4*>(bufc + rofs + (((ks*4+lg)^lx7)<<4));
    }
    FragU af[4][2];
    #pragma unroll
    for (int mf=0; mf<4; mf++){
      const int rofs = (wm*128 + mf*16 + ln)*128;
      #pragma unroll
      for (int ks=0; ks<2; ks++)
        af[mf][ks].q = *reinterpret_cast<const u32x4*>(bufc + rofs + (((ks*4+lg)^lx7)<<4));
    }
    if (t+1 < nt) stA(cur^1, t+1);
    __builtin_amdgcn_s_barrier();
    __builtin_amdgcn_s_setprio(1);
    #pragma unroll
    for (int ks=0; ks<2; ks++){
      #pragma unroll
      for (int mf=0; mf<4; mf++){
        #pragma unroll
        for (int ni=0; ni<3; ni++)
          acc[mf][ni] = __builtin_amdgcn_mfma_f32_16x16x32_bf16(af[mf][ks].v, bfr[ni][ks].v, acc[mf][ni], 0,0,0);
      }
    }
    __builtin_amdgcn_s_setprio(0);
    // fence: all waves' B-frag reads done before crossing; licenses stB below.
    asm volatile("s_waitcnt lgkmcnt(0)" ::: "memory");
    __builtin_amdgcn_s_barrier();

    // ---- phase 1: A m-frags 4..7; stage B(t+2) -> B[cur] ----
    FragU ag[4][2];
    #pragma unroll
    for (int mf=0; mf<4; mf++){
      const int rofs = (wm*128 + (mf+4)*16 + ln)*128;
      #pragma unroll
      for (int ks=0; ks<2; ks++)
        ag[mf][ks].q = *reinterpret_cast<const u32x4*>(bufc + rofs + (((ks*4+lg)^lx7)<<4));
    }
    if (t+2 < nt) stB(cur, t+2);
    __builtin_amdgcn_s_barrier();
    __builtin_amdgcn_s_setprio(1);
    #pragma unroll
    for (int ks=0; ks<2; ks++){
      #pragma unroll
      for (int mf=0; mf<4; mf++){
        #pragma unroll
        for (int ni=0; ni<3; ni++)
          acc[mf+4][ni] = __builtin_amdgcn_mfma_f32_16x16x32_bf16(ag[mf][ks].v, bfr[ni][ks].v, acc[mf+4][ni], 0,0,0);
      }
    }
    __builtin_amdgcn_s_setprio(0);
    // ---- iteration boundary: counted wait (never 0 mid-loop) ----
    if (t+1 < nt){
      if (t+2 < nt) asm volatile("s_waitcnt vmcnt(3)" ::: "memory");
      else          asm volatile("s_waitcnt vmcnt(0)" ::: "memory");
    }
    __builtin_amdgcn_s_barrier();
    asm volatile("" ::: "memory");
  }

  #pragma unroll
  for (int mi=0; mi<8; mi++){
    #pragma unroll
    for (int ni=0; ni<3; ni++){
      const int row0 = bm*256 + wm*128 + mi*16 + lg*4;
      const int col  = bn*192 + wn*48  + ni*16 + ln;
      #pragma unroll
      for (int r=0; r<4; r++)
        C[(size_t)(row0+r)*N + col] = acc[mi][ni][r];
    }
  }
}

// ---------------------------------------------------------------------------
// 128x256-tile variant (full-coverage shape for M=2048,N=4096: 256 blocks).
// 2 fat phases/K-tile (16 MFMA each); wave = 64x64, acc[4][4]; A stages 2
// loads, B stages 4.  LDS 96KB = 2 x (A 16KB + B 32KB).
// ---------------------------------------------------------------------------
__global__ __launch_bounds__(512, 2)
void gemm_pkB(const u32* __restrict__ A, const u32* __restrict__ B,
              float* __restrict__ C, int M, int N, int K)  // K = u32 per row
{
  extern __shared__ char smem[];   // 98304 B: [buf2][ A 16KB | B 32KB ]
  const int tid  = threadIdx.x;
  const int lane = tid & 63;
  const int w    = tid >> 6;       // 0..7
  const int wm = w >> 2, wn = w & 3;
  const int ln = lane & 15, lg = lane >> 4;

  const int nbm = M >> 7, nbn = N >> 8;
  const int nwg = nbm * nbn;
  const int swz = (blockIdx.x & 7) * (nwg >> 3) + (blockIdx.x >> 3);
  const int bm = swz % nbm, bn = swz / nbm;

  const size_t rbA = (size_t)K * 4;          // row bytes
  const int lrow  = lane >> 3;               // 0..7
  const int lslot = (lane & 7) ^ (lrow & 7); // pre-swizzled source slot
  const char* As0 = (const char*)A + (size_t)(bm*128 + w*8 + lrow)*rbA + lslot*16;
  const char* Bs0 = (const char*)B + (size_t)(bn*256 + w*8 + lrow)*rbA + lslot*16;

  auto stA = [&](int buf, int t) {
    const char* s = As0 + ((size_t)t << 7);
    char* d = smem + buf*49152 + w*1024;
    gload16(s,            d);
    gload16(s +  64*rbA,  d + 8192);
  };
  auto stB = [&](int buf, int t) {
    const char* s = Bs0 + ((size_t)t << 7);
    char* d = smem + buf*49152 + 16384 + w*1024;
    gload16(s,            d);
    gload16(s +  64*rbA,  d + 8192);
    gload16(s + 128*rbA,  d + 16384);
    gload16(s + 192*rbA,  d + 24576);
  };

  f32x4 z = {0.f,0.f,0.f,0.f};
  f32x4 acc[4][4];
  #pragma unroll
  for (int i=0;i<4;i++){
    #pragma unroll
    for (int j=0;j<4;j++) acc[i][j] = z;
  }

  const int nt = K >> 5;           // K-tiles of 32 u32 (=64 bf16)
  stA(0, 0); stB(0, 0);            // 6 loads
  if (nt > 1) { stB(1, 1);         // +4
    asm volatile("s_waitcnt vmcnt(4)" ::: "memory");   // tile0's 6 complete
  } else {
    asm volatile("s_waitcnt vmcnt(0)" ::: "memory");
  }
  __builtin_amdgcn_s_barrier();
  asm volatile("" ::: "memory");

  const int boff0 = 16384;
  const int lx7   = ln & 7;

  for (int t = 0; t < nt; ++t){
    const int cur = t & 1;
    const char* bufc = smem + cur*49152;

    // ---- phase 0: all B frags + A m-frags 0..1; stage A(t+1) ----
    FragU bfr[4][2];
    #pragma unroll
    for (int ni=0; ni<4; ni++){
      const int rofs = boff0 + (wn*64 + ni*16 + ln)*128;
      #pragma unroll
      for (int ks=0; ks<2; ks++)
        bfr[ni][ks].q = *reinterpret_cast<const u32x4*>(bufc + rofs + (((ks*4+lg)^lx7)<<4));
    }
    FragU af[2][2];
    #pragma unroll
    for (int mf=0; mf<2; mf++){
      const int rofs = (wm*64 + mf*16 + ln)*128;
      #pragma unroll
      for (int ks=0; ks<2; ks++)
        af[mf][ks].q = *reinterpret_cast<const u32x4*>(bufc + rofs + (((ks*4+lg)^lx7)<<4));
    }
    if (t+1 < nt) stA(cur^1, t+1);
    __builtin_amdgcn_s_barrier();
    __builtin_amdgcn_s_setprio(1);
    #pragma unroll
    for (int ks=0; ks<2; ks++){
      #pragma unroll
      for (int mf=0; mf<2; mf++){
        #pragma unroll
        for (int ni=0; ni<4; ni++)
          acc[mf][ni] = __builtin_amdgcn_mfma_f32_16x16x32_bf16(af[mf][ks].v, bfr[ni][ks].v, acc[mf][ni], 0,0,0);
      }
    }
    __builtin_amdgcn_s_setprio(0);
    asm volatile("s_waitcnt lgkmcnt(0)" ::: "memory");
    __builtin_amdgcn_s_barrier();

    // ---- phase 1: A m-frags 2..3; stage B(t+2) -> B[cur] ----
    FragU ag[2][2];
    #pragma unroll
    for (int mf=0; mf<2; mf++){
      const int rofs = (wm*64 + (mf+2)*16 + ln)*128;
      #pragma unroll
      for (int ks=0; ks<2; ks++)
        ag[mf][ks].q = *reinterpret_cast<const u32x4*>(bufc + rofs + (((ks*4+lg)^lx7)<<4));
    }
    if (t+2 < nt) stB(cur, t+2);
    __builtin_amdgcn_s_barrier();
    __builtin_amdgcn_s_setprio(1);
    #pragma unroll
    for (int ks=0; ks<2; ks++){
      #pragma unroll
      for (int mf=0; mf<2; mf++){
        #pragma unroll
        for (int ni=0; ni<4; ni++)
          acc[mf+2][ni] = __builtin_amdgcn_mfma_f32_16x16x32_bf16(ag[mf][ks].v, bfr[ni][ks].v, acc[mf+2][ni], 0,0,0);
      }
    }
    __builtin_amdgcn_s_setprio(0);
    // ---- iteration boundary: counted wait (never 0 mid-loop) ----
    if (t+1 < nt){
      if (t+2 < nt) asm volatile("s_waitcnt vmcnt(4)" ::: "memory");
      else          asm volatile("s_waitcnt vmcnt(0)" ::: "memory");
    }
    __builtin_amdgcn_s_barrier();
    asm volatile("" ::: "memory");
  }

  #pragma unroll
  for (int mi=0; mi<4; mi++){
    #pragma unroll
    for (int ni=0; ni<4; ni++){
      const int row0 = bm*128 + wm*64 + mi*16 + lg*4;
      const int col  = bn*256 + wn*64 + ni*16 + ln;
      #pragma unroll
      for (int r=0; r<4; r++)
        C[(size_t)(row0+r)*N + col] = acc[mi][ni][r];
    }
  }
}

// ---------------------------------------------------------------------------
// Gather old paged cache into contiguous PACKED ws buffers.
// k_all  : u32 [B][HKV][1024][128]   v_allT : u32 [B][HKV][128][1024]
// ---------------------------------------------------------------------------
__global__ __launch_bounds__(256)
void copy_cache(const float* __restrict__ k_cache, const float* __restrict__ v_cache,
                const int* __restrict__ page_table,
                u32* __restrict__ k_all, u32* __restrict__ v_allT)
{
  __shared__ float tb[32][129];
  const int id = blockIdx.x;
  const int jt = id & 31, h = (id>>5)&7, b = id>>8;
  const int tid = threadIdx.x;
  const int j0 = jt*32;
  {
    int r = tid>>3, c = tid&7;
    int j = j0 + r;
    int page = page_table[b*64 + (j>>4)];
    int slot = j & 15;
    const float* ks = k_cache + (size_t)((page*16 + slot)*8 + h)*128;
    const float* vs = v_cache + (size_t)((page*16 + slot)*8 + h)*128;
    u32* kd = k_all + ((size_t)(b*8+h)*1024 + j)*128;
    #pragma unroll
    for (int i=0;i<4;i++){
      int d0 = (c + 8*i)*4;
      float4 k4 = *reinterpret_cast<const float4*>(ks + d0);
      *reinterpret_cast<u32x4*>(kd + d0) =
        (u32x4){ pack2(k4.x), pack2(k4.y), pack2(k4.z), pack2(k4.w) };
      float4 v4 = *reinterpret_cast<const float4*>(vs + d0);
      tb[r][d0+0]=v4.x; tb[r][d0+1]=v4.y; tb[r][d0+2]=v4.z; tb[r][d0+3]=v4.w;
    }
  }
  __syncthreads();
  {
    int dout = tid>>1, jh = tid&1;
    u32* vd = v_allT + ((size_t)(b*8+h)*128 + dout)*1024 + j0 + jh*16;
    #pragma unroll
    for (int i=0;i<4;i++){
      u32x4 o;
      o.x = pack2(tb[jh*16 + i*4 + 0][dout]);
      o.y = pack2(tb[jh*16 + i*4 + 1][dout]);
      o.z = pack2(tb[jh*16 + i*4 + 2][dout]);
      o.w = pack2(tb[jh*16 + i*4 + 3][dout]);
      *reinterpret_cast<u32x4*>(vd + i*4) = o;
    }
  }
}

// ---------------------------------------------------------------------------
// Per-head RMSNorm + partial RoPE + scatter new K/V (packed) into k_all/v_allT.
// ---------------------------------------------------------------------------
__global__ __launch_bounds__(256)
void norm_rope_scatter(float* __restrict__ qkv, const float* __restrict__ cosT,
                       const float* __restrict__ sinT, const int* __restrict__ positions,
                       const int* __restrict__ cache_seqlens,
                       const float* __restrict__ qw, const float* __restrict__ kw,
                       u32* __restrict__ k_all, u32* __restrict__ v_allT)
{
  const int t = blockIdx.x;
  const int lane = threadIdx.x & 63;
  const int w = threadIdx.x >> 6;
  const int b = t >> 9;        // QL = 512
  const int q = t & 511;
  const int pos  = positions[t];
  const int cpos = cache_seqlens[b] + q;
  for (int it=0; it<12; ++it){
    int h = it*4 + w;          // 0..47
    float* xp = qkv + (size_t)t*6144 + h*128 + 2*lane;
    float2 x = *reinterpret_cast<const float2*>(xp);
    if (h < 40){               // q + k heads get RMSNorm + RoPE
      float ss = x.x*x.x + x.y*x.y;
      #pragma unroll
      for (int mk=1; mk<64; mk<<=1) ss += __shfl_xor(ss, mk);
      float var = ss*(1.0f/128.0f) + 1e-6f;
      float rq = rsqrtf(var);
      rq = rq*(1.5f - 0.5f*var*rq*rq);   // Newton refine
      const float* wt = (h<32) ? qw : kw;
      x.x *= rq*wt[2*lane]; x.y *= rq*wt[2*lane+1];
      float px = __shfl_xor(x.x, 16);
      float py = __shfl_xor(x.y, 16);
      if (lane < 32){
        int ci = pos*32 + 2*(lane&15);
        float2 cc = *reinterpret_cast<const float2*>(cosT + ci);
        float2 sc = *reinterpret_cast<const float2*>(sinT + ci);
        if (lane < 16){ x.x = x.x*cc.x - px*sc.x; x.y = x.y*cc.y - py*sc.y; }
        else          { x.x = x.x*cc.x + px*sc.x; x.y = x.y*cc.y + py*sc.y; }
      }
    }
    if (h < 32){
      *reinterpret_cast<float2*>(xp) = x;   // q back in place (fp32)
    } else if (h < 40){
      u32* kp = k_all + ((size_t)(b*8 + (h-32))*1024 + cpos)*128 + 2*lane;
      kp[0] = pack2(x.x); kp[1] = pack2(x.y);
    } else {
      u32* vp = v_allT + ((size_t)(b*8 + (h-40))*128 + 2*lane)*1024 + cpos;
      vp[0]    = pack2(x.x);
      vp[1024] = pack2(x.y);
    }
  }
}

// ---------------------------------------------------------------------------
// Fused GQA causal attention.  Block = (b, kv-head, g, 64-row q tile),
// 4 waves x 16 q-rows. KV tiles of 32, split-bf16 MFMA, fp32 online softmax.
// K/V come pre-packed; output written PACKED for the O-proj GEMM.
// ---------------------------------------------------------------------------
__global__ __launch_bounds__(256)
void attn_fused(const float* __restrict__ qkv, const u32* __restrict__ k_all,
                const u32* __restrict__ v_allT, const int* __restrict__ cache_seqlens,
                u32* __restrict__ attnO)
{
  __shared__ u16 Ks[32*256];     // [kv][k'=2d+s]  (swizzled)
  __shared__ u16 Vs[128*64];     // [d][k''=2kv+s] (swizzled)
  __shared__ float Pl[4*16*32];  // per-wave P tile (swizzled)
  const int tid = threadIdx.x, lane = tid&63, w = tid>>6;
  const int ln = lane&15, lg = lane>>4;
  const int id = blockIdx.x;
  const int qt = id & 7, g = (id>>3)&3, kvh = (id>>5)&7, b = id>>8;
  const int cs = cache_seqlens[b];
  const int h  = kvh*4 + g;
  const int q0 = qt*64 + w*16;
  const float SCALE = 0.08838834764831845f;  // 1/sqrt(128)
  f32x4 z = {0.f,0.f,0.f,0.f};

  FragU qf[8];
  {
    const float* qp = qkv + (size_t)(b*512 + q0 + ln)*6144 + h*128;
    #pragma unroll
    for (int ks=0; ks<8; ks++){
      int d0 = ks*16 + lg*4;
      float4 v4 = *reinterpret_cast<const float4*>(qp + d0);
      qf[ks].q = (u32x4){ pack2(v4.x*SCALE), pack2(v4.y*SCALE),
                          pack2(v4.z*SCALE), pack2(v4.w*SCALE) };
    }
  }
  f32x4 O[8];
  #pragma unroll
  for (int i=0;i<8;i++) O[i] = z;
  float m[4] = {-1e30f,-1e30f,-1e30f,-1e30f};
  float l[4] = {0.f,0.f,0.f,0.f};
  const int prow0 = cs + q0 + lg*4;
  const int ntiles = (cs + qt*64 + 64 + 31) >> 5;
  const u32* kbase = k_all  + (size_t)(b*8+kvh)*1024*128;
  const u32* vbase = v_allT + (size_t)(b*8+kvh)*128*1024;

  for (int tile=0; tile<ntiles; ++tile){
    const int kv0 = tile*32;
    __syncthreads();
    {   // stage K tile (32 kv x 128 d), already packed
      int r = tid>>3;
      const u32* kp = kbase + (size_t)(kv0 + r)*128;
      #pragma unroll
      for (int c2=0;c2<4;c2++){
        int d0 = ((tid&7) + 8*c2)*4;
        u32x4 pk = *reinterpret_cast<const u32x4*>(kp + d0);
        *reinterpret_cast<u32x4*>(&Ks[(r*256 + d0*2) ^ ((r&7)<<3)]) = pk;
      }
    }
    {   // stage V tile (transposed source), already packed
      int dr = tid>>1;
      const u32* vp = vbase + (size_t)dr*1024 + kv0;
      #pragma unroll
      for (int c2=0;c2<4;c2++){
        int kl0 = ((tid&1)*4 + c2)*4;
        u32x4 pv4 = *reinterpret_cast<const u32x4*>(vp + kl0);
        *reinterpret_cast<u32x4*>(&Vs[(dr*64 + kl0*2) ^ ((dr&7)<<3)]) = pv4;
      }
    }
    __syncthreads();
    // S = Q K^T (split-bf16 over K'=256)
    f32x4 s[2]; s[0]=z; s[1]=z;
    #pragma unroll
    for (int ks=0; ks<8; ks++){
      int kb = ks*32 + lg*8;
      #pragma unroll
      for (int n=0;n<2;n++){
        int kr = n*16 + ln;
        FragU kf;
        kf.q = *reinterpret_cast<const u32x4*>(&Ks[(kr*256 + kb) ^ ((kr&7)<<3)]);
        s[n] = __builtin_amdgcn_mfma_f32_16x16x32_bf16(qf[ks].v, kf.v, s[n], 0,0,0);
      }
    }
    // online softmax (rows = lg*4+r)
    float mx[4];
    #pragma unroll
    for (int r=0;r<4;r++){
      int pr = prow0 + r;
      float a0 = (kv0 + ln      <= pr) ? s[0][r] : -1e30f;
      float a1 = (kv0 + 16 + ln <= pr) ? s[1][r] : -1e30f;
      mx[r] = fmaxf(a0, a1);
    }
    #pragma unroll
    for (int off=1; off<16; off<<=1){
      #pragma unroll
      for (int r=0;r<4;r++) mx[r] = fmaxf(mx[r], __shfl_xor(mx[r], off));
    }
    float corr[4];
    #pragma unroll
    for (int r=0;r<4;r++){
      float mn = fmaxf(m[r], mx[r]);
      corr[r] = __expf(m[r] - mn);
      m[r] = mn;
    }
    float pv[2][4], ps[4] = {0.f,0.f,0.f,0.f};
    #pragma unroll
    for (int n=0;n<2;n++){
      #pragma unroll
      for (int r=0;r<4;r++){
        bool ok = (kv0 + n*16 + ln) <= (prow0 + r);
        float p = ok ? __expf(s[n][r] - m[r]) : 0.f;
        pv[n][r] = p;
        ps[r] += p;
      }
    }
    #pragma unroll
    for (int off=1; off<16; off<<=1){
      #pragma unroll
      for (int r=0;r<4;r++) ps[r] += __shfl_xor(ps[r], off);
    }
    #pragma unroll
    for (int r=0;r<4;r++) l[r] = l[r]*corr[r] + ps[r];
    #pragma unroll
    for (int nf=0; nf<8; nf++){
      #pragma unroll
      for (int r=0;r<4;r++) O[nf][r] = O[nf][r]*corr[r];
    }
    // P -> per-wave LDS (swizzled), then build duplicated hi/lo A-frags
    #pragma unroll
    for (int n=0;n<2;n++){
      #pragma unroll
      for (int r=0;r<4;r++){
        int row = lg*4 + r;
        Pl[w*512 + ((row*32 + n*16 + ln) ^ ((row&7)<<2))] = pv[n][r];
      }
    }
    FragU pah[2], pal[2];
    #pragma unroll
    for (int ks2=0; ks2<2; ks2++){
      int fi = (ln*32 + ks2*16 + lg*4) ^ ((ln&7)<<2);
      float4 pp = *reinterpret_cast<const float4*>(&Pl[w*512 + fi]);
      float parr[4] = {pp.x, pp.y, pp.z, pp.w};
      #pragma unroll
      for (int i=0;i<4;i++){
        u16 hh = bfhi(parr[i]);
        u16 ll = bfhi(parr[i] - bff(hh));
        pah[ks2].us[2*i] = hh; pah[ks2].us[2*i+1] = hh;
        pal[ks2].us[2*i] = ll; pal[ks2].us[2*i+1] = ll;
      }
    }
    // O += (Ph+Pl) x (Vh+Vl)
    #pragma unroll
    for (int nf=0; nf<8; nf++){
      int dr = nf*16 + ln;
      #pragma unroll
      for (int ks2=0; ks2<2; ks2++){
        FragU vf;
        vf.q = *reinterpret_cast<const u32x4*>(&Vs[(dr*64 + ks2*32 + lg*8) ^ ((dr&7)<<3)]);
        O[nf] = __builtin_amdgcn_mfma_f32_16x16x32_bf16(pah[ks2].v, vf.v, O[nf], 0,0,0);
        O[nf] = __builtin_amdgcn_mfma_f32_16x16x32_bf16(pal[ks2].v, vf.v, O[nf], 0,0,0);
      }
    }
  }
  float il[4];
  #pragma unroll
  for (int r=0;r<4;r++) il[r] = 1.0f / l[r];
  u32* op = attnO + (size_t)(b*512 + q0 + lg*4)*4096 + h*128 + ln;
  #pragma unroll
  for (int nf=0; nf<8; nf++){
    #pragma unroll
    for (int r=0;r<4;r++)
      op[(size_t)r*4096 + nf*16] = pack2(O[nf][r] * il[r]);
  }
}

// ---------------------------------------------------------------------------
extern "C" void kernel_launch(void* const* d_in, const int* in_sizes, int n_in,
                              void* d_out, int out_size, void* d_ws, size_t ws_size,
                              hipStream_t stream) {
  const float* hidden    = (const float*)d_in[0];
  const float* cosT      = (const float*)d_in[1];
  const float* sinT      = (const float*)d_in[2];
  const int*   positions = (const int*)  d_in[3];
  const float* k_cache   = (const float*)d_in[4];
  const float* v_cache   = (const float*)d_in[5];
  const int*   page_tab  = (const int*)  d_in[6];
  const int*   cache_sl  = (const int*)  d_in[7];
  const float* qkv_w     = (const float*)d_in[9];
  const float* o_w       = (const float*)d_in[10];
  const float* qnw       = (const float*)d_in[11];
  const float* knw       = (const float*)d_in[12];
  float* out = (float*)d_out;

  u32* ws      = (u32*)d_ws;
  float* qkv   = (float*)ws;                // 2048*6144        = 12582912
  u32* k_all   = ws      + 12582912;        // 4*8*1024*128     =  4194304
  u32* v_allT  = k_all   + 4194304;         //                  =  4194304
  u32* attnPk  = v_allT  + 4194304;         // 2048*4096        =  8388608
  u32* hidPk   = attnPk  + 8388608;         // 2048*4096        =  8388608
  u32* qkvwPk  = hidPk   + 8388608;         // 6144*4096        = 25165824
  u32* owPk    = qkvwPk  + 25165824;        // 4096*4096        = 16777216
  (void)in_sizes; (void)n_in; (void)out_size; (void)ws_size;

  (void)hipFuncSetAttribute(reinterpret_cast<const void*>(gemm_pkA),
                            hipFuncAttributeMaxDynamicSharedMemorySize, 114688);
  (void)hipFuncSetAttribute(reinterpret_cast<const void*>(gemm_pkB),
                            hipFuncAttributeMaxDynamicSharedMemorySize, 98304);

  hipLaunchKernelGGL(split_pack, dim3(1024), dim3(256), 0, stream,
                     hidden, hidPk, 2097152);
  hipLaunchKernelGGL(split_pack, dim3(1024), dim3(256), 0, stream,
                     qkv_w, qkvwPk, 6291456);
  hipLaunchKernelGGL(split_pack, dim3(1024), dim3(256), 0, stream,
                     o_w, owPk, 4194304);
  hipLaunchKernelGGL(copy_cache, dim3(1024), dim3(256), 0, stream,
                     k_cache, v_cache, page_tab, k_all, v_allT);
  hipLaunchKernelGGL(gemm_pkA, dim3(256), dim3(512), 114688, stream,
                     hidPk, qkvwPk, qkv, 2048, 6144, 4096);
  hipLaunchKernelGGL(norm_rope_scatter, dim3(2048), dim3(256), 0, stream,
                     qkv, cosT, sinT, positions, cache_sl, qnw, knw, k_all, v_allT);
  hipLaunchKernelGGL(attn_fused, dim3(1024), dim3(256), 0, stream,
                     qkv, k_all, v_allT, cache_sl, attnPk);
  hipLaunchKernelGGL(gemm_pkB, dim3(256), dim3(512), 98304, stream,
                     attnPk, owPk, out, 2048, 4096, 4096);
}